// Round 11
// baseline (191.342 us; speedup 1.0000x reference)
//
#include <hip/hip_runtime.h>
#include <hip/hip_bf16.h>

#define S_LEN 2048
#define NH 32
#define D_DIM 128
#define LAST_Q 64
#define SCALE_F 0.08838834764831845f
#define QSCALE (0.08838834764831845f * 1.4426950408889634f)  // scale * log2(e)
#define RESCALE_THR 11.54f

typedef __attribute__((ext_vector_type(8))) short bf16x8;
typedef __attribute__((ext_vector_type(4))) float f32x4;
typedef unsigned long long u64;
typedef unsigned int u32;
typedef unsigned short u16;

static __device__ __forceinline__ u16 f32_bf16(float f) {
  u32 u = __float_as_uint(f);
  u32 r = (u + 0x7FFFu + ((u >> 16) & 1u)) >> 16;
  return (u16)r;
}

static __device__ __forceinline__ u32 cvt_pk_bf16(float lo, float hi) {
  u32 r;
  asm("v_cvt_pk_bf16_f32 %0, %1, %2" : "=v"(r) : "v"(lo), "v"(hi));
  return r;
}

// ---------------- Stage 0: preconvert to PRE-SWIZZLED bf16 layouts (R7 verbatim) ----------------
__global__ __launch_bounds__(256) void conv_kernel(const float* __restrict__ k,
                                                   const float* __restrict__ v,
                                                   u16* __restrict__ kpre,
                                                   u16* __restrict__ vpre) {
  int bid = blockIdx.x;
  int t = bid & 31, h = bid >> 5;
  int tid = threadIdx.x;
  int c0 = t * 64;
  __shared__ u16 Vb[64][136];
  for (int i = tid; i < 512; i += 256) {
    int r = i >> 3, s = i & 7;
    const float* srcp = v + ((size_t)(h * S_LEN + c0 + r)) * D_DIM + s * 16;
    float4 f0 = *(const float4*)(srcp);
    float4 f1 = *(const float4*)(srcp + 4);
    float4 f2 = *(const float4*)(srcp + 8);
    float4 f3 = *(const float4*)(srcp + 12);
    bf16x8 t0, t1;
    t0[0] = (short)f32_bf16(f0.x); t0[1] = (short)f32_bf16(f0.y);
    t0[2] = (short)f32_bf16(f0.z); t0[3] = (short)f32_bf16(f0.w);
    t0[4] = (short)f32_bf16(f1.x); t0[5] = (short)f32_bf16(f1.y);
    t0[6] = (short)f32_bf16(f1.z); t0[7] = (short)f32_bf16(f1.w);
    t1[0] = (short)f32_bf16(f2.x); t1[1] = (short)f32_bf16(f2.y);
    t1[2] = (short)f32_bf16(f2.z); t1[3] = (short)f32_bf16(f2.w);
    t1[4] = (short)f32_bf16(f3.x); t1[5] = (short)f32_bf16(f3.y);
    t1[6] = (short)f32_bf16(f3.z); t1[7] = (short)f32_bf16(f3.w);
    *(bf16x8*)&Vb[r][s * 16] = t0;
    *(bf16x8*)&Vb[r][s * 16 + 8] = t1;
  }
  u16* kp = kpre + (size_t)h * 262144 + (size_t)t * 8192;
#pragma unroll
  for (int j = 0; j < 4; ++j) {
    int p = j * 256 + tid;
    int r = p >> 4;
    int g = (p & 15) ^ (r & 15);
    const float* srcp = k + ((size_t)(h * S_LEN + c0 + r)) * D_DIM + g * 8;
    float4 a = *(const float4*)srcp;
    float4 b = *(const float4*)(srcp + 4);
    bf16x8 o;
    o[0] = (short)f32_bf16(a.x); o[1] = (short)f32_bf16(a.y);
    o[2] = (short)f32_bf16(a.z); o[3] = (short)f32_bf16(a.w);
    o[4] = (short)f32_bf16(b.x); o[5] = (short)f32_bf16(b.y);
    o[6] = (short)f32_bf16(b.z); o[7] = (short)f32_bf16(b.w);
    *(bf16x8*)(kp + p * 8) = o;
  }
  __syncthreads();
  u16* vp = vpre + (size_t)h * 262144 + (size_t)t * 8192;
#pragma unroll
  for (int j = 0; j < 4; ++j) {
    int p = j * 256 + tid;
    int d = p >> 3;
    int cb = (p & 7) ^ (d & 7);
    bf16x8 g;
#pragma unroll
    for (int e = 0; e < 8; ++e) g[e] = (short)Vb[cb * 8 + e][d];
    *(bf16x8*)(vp + p * 8) = g;
  }
}

// ---------------- Stage 1a: est scores (f32 VALU — selection-stable) ----------------
__global__ __launch_bounds__(256) void est_kernel(const float* __restrict__ q,
                                                  const float* __restrict__ k,
                                                  float* __restrict__ scores) {
  int cc = blockIdx.x;
  int h = blockIdx.y;
  int tid = threadIdx.x;
  int ty = tid >> 4, tx = tid & 15;
  __shared__ float Qs[64][36];
  __shared__ float Ks[64][36];
  float acc[4][4];
#pragma unroll
  for (int i = 0; i < 4; ++i)
#pragma unroll
    for (int j = 0; j < 4; ++j) acc[i][j] = 0.f;
  const float* qbase = q + ((size_t)h * S_LEN + (S_LEN - LAST_Q)) * D_DIM;
  const float* kbase = k + ((size_t)h * S_LEN + cc * 64) * D_DIM;
  for (int dc = 0; dc < 4; ++dc) {
    __syncthreads();
    for (int i = tid; i < 512; i += 256) {
      int r = i >> 3, s = i & 7;
      float4 a = *(const float4*)(qbase + (size_t)r * D_DIM + dc * 32 + s * 4);
      *(float4*)&Qs[r][s * 4] = a;
      float4 b = *(const float4*)(kbase + (size_t)r * D_DIM + dc * 32 + s * 4);
      *(float4*)&Ks[r][s * 4] = b;
    }
    __syncthreads();
#pragma unroll
    for (int d4 = 0; d4 < 8; ++d4) {
      float4 qv[4], kv[4];
#pragma unroll
      for (int i = 0; i < 4; ++i) qv[i] = *(const float4*)&Qs[ty + 16 * i][d4 * 4];
#pragma unroll
      for (int j = 0; j < 4; ++j) kv[j] = *(const float4*)&Ks[tx + 16 * j][d4 * 4];
#pragma unroll
      for (int i = 0; i < 4; ++i)
#pragma unroll
        for (int j = 0; j < 4; ++j)
          acc[i][j] += qv[i].x * kv[j].x + qv[i].y * kv[j].y + qv[i].z * kv[j].z + qv[i].w * kv[j].w;
    }
  }
#pragma unroll
  for (int i = 0; i < 4; ++i) {
    int rl = ty + 16 * i;
    int rg = (S_LEN - LAST_Q) + rl;
#pragma unroll
    for (int j = 0; j < 4; ++j) {
      int cg = cc * 64 + tx + 16 * j;
      float vv = (cg <= rg) ? acc[i][j] * SCALE_F : -1e30f;
      scores[((size_t)h * LAST_Q + rl) * S_LEN + cg] = vv;
    }
  }
}

// ---------------- Stage 1b: softmax partials (grid 32 x 16, 4 rows each) ----------------
__global__ __launch_bounds__(256) void soft_partial_kernel(const float* __restrict__ scores,
                                                           float* __restrict__ part) {
  int h = blockIdx.x, rg = blockIdx.y;
  int tid = threadIdx.x;
  int wave = tid >> 6, lane = tid & 63;
  __shared__ float vs[2048];
  __shared__ float ss[2048];
  __shared__ float red[4];
  int i0 = tid * 8;
#pragma unroll
  for (int e = 0; e < 8; ++e) { vs[i0 + e] = 0.f; ss[i0 + e] = 0.f; }
  for (int rr = 0; rr < 4; ++rr) {
    int r = rg * 4 + rr;
    const float* sp = scores + ((size_t)h * LAST_Q + r) * S_LEN;
    float4 a = *(const float4*)(sp + i0);
    float4 b = *(const float4*)(sp + i0 + 4);
    float x[8] = {a.x, a.y, a.z, a.w, b.x, b.y, b.z, b.w};
    float wm = -1e30f;
#pragma unroll
    for (int e = 0; e < 8; ++e) wm = fmaxf(wm, x[e]);
#pragma unroll
    for (int mk = 1; mk < 64; mk <<= 1) wm = fmaxf(wm, __shfl_xor(wm, mk, 64));
    __syncthreads();
    if (lane == 0) red[wave] = wm;
    __syncthreads();
    float m = fmaxf(fmaxf(red[0], red[1]), fmaxf(red[2], red[3]));
    float psum = 0.f;
#pragma unroll
    for (int e = 0; e < 8; ++e) { x[e] = __expf(x[e] - m); psum += x[e]; }
#pragma unroll
    for (int mk = 1; mk < 64; mk <<= 1) psum += __shfl_xor(psum, mk, 64);
    __syncthreads();
    if (lane == 0) red[wave] = psum;
    __syncthreads();
    float inv = 1.f / (red[0] + red[1] + red[2] + red[3]);
    int rgl = (S_LEN - LAST_Q) + r;
#pragma unroll
    for (int e = 0; e < 8; ++e) {
      float p = x[e] * inv;
      int i = i0 + e;
      vs[i] += p;
      int d = rgl - i;
      if (d >= 0) ss[d] += p;
    }
  }
  __syncthreads();
  float* pb = part + ((size_t)(h * 16 + rg)) * 4096;
#pragma unroll
  for (int e = 0; e < 8; ++e) { pb[i0 + e] = vs[i0 + e]; pb[2048 + i0 + e] = ss[i0 + e]; }
}

// ---------------- Stage 1c: fused reduce + top-k -> bitmasks ----------------
__global__ __launch_bounds__(256) void topk_kernel(const float* __restrict__ part,
                                                   u64* __restrict__ vbits,
                                                   u64* __restrict__ sbits) {
  int h = blockIdx.x;
  int which = blockIdx.y;
  u64* dst = which ? (sbits + h * 32) : (vbits + h * 32);
  u32 K = which ? 512u : 256u;
  int ninf = which ? 64 : 4;
  int tid = threadIdx.x;
  int lane = tid & 63, wid = tid >> 6;
  __shared__ u32 keys[2048];
  __shared__ u32 hist[256];
  __shared__ u32 wpart[4];
  __shared__ u32 sh_pref, sh_kth;
  __shared__ u64 mbw[32];
  int i0 = tid * 8;
  float accv[8] = {0.f, 0.f, 0.f, 0.f, 0.f, 0.f, 0.f, 0.f};
  for (int rg = 0; rg < 16; ++rg) {
    const float* pp = part + ((size_t)(h * 16 + rg)) * 4096 + which * 2048 + i0;
    float4 a = *(const float4*)pp;
    float4 b = *(const float4*)(pp + 4);
    accv[0] += a.x; accv[1] += a.y; accv[2] += a.z; accv[3] += a.w;
    accv[4] += b.x; accv[5] += b.y; accv[6] += b.z; accv[7] += b.w;
  }
#pragma unroll
  for (int e = 0; e < 8; ++e) {
    int i = i0 + e;
    keys[i] = (i < ninf) ? 0x7F800000u : __float_as_uint(accv[e]);
  }
  __syncthreads();
  u32 prefix = 0;
  u32 kth = K;
  for (int shift = 24; shift >= 0; shift -= 8) {
    hist[tid] = 0;
    __syncthreads();
#pragma unroll
    for (int e = 0; e < 8; ++e) {
      u32 kk = keys[i0 + e];
      if (shift == 24 || (kk >> (shift + 8)) == (prefix >> (shift + 8)))
        atomicAdd(&hist[(kk >> shift) & 255], 1u);
    }
    __syncthreads();
    u32 v = hist[tid];
    u32 x = v;
#pragma unroll
    for (int off = 1; off < 64; off <<= 1) {
      u32 o = __shfl_up(x, off, 64);
      if (lane >= off) x += o;
    }
    if (lane == 63) wpart[wid] = x;
    __syncthreads();
    u32 base = 0;
    for (int w2 = 0; w2 < wid; ++w2) base += wpart[w2];
    u32 T = wpart[0] + wpart[1] + wpart[2] + wpart[3];
    u32 Pincl = x + base;
    u32 Sb = T - Pincl + v;
    u32 Sn = T - Pincl;
    if (Sb >= kth && Sn < kth) {
      sh_pref = prefix | ((u32)tid << shift);
      sh_kth = kth - Sn;
    }
    __syncthreads();
    prefix = sh_pref;
    kth = sh_kth;
    __syncthreads();
  }
  u32 t = prefix;
  u32 cnt = 0;
#pragma unroll
  for (int e = 0; e < 8; ++e) cnt += (keys[i0 + e] == t) ? 1u : 0u;
  u32 x = cnt;
#pragma unroll
  for (int off = 1; off < 64; off <<= 1) {
    u32 o = __shfl_up(x, off, 64);
    if (lane >= off) x += o;
  }
  if (lane == 63) wpart[wid] = x;
  __syncthreads();
  u32 base = 0;
  for (int w2 = 0; w2 < wid; ++w2) base += wpart[w2];
  u32 exc = x + base - cnt;
  unsigned char myb = 0;
  u32 seen = 0;
#pragma unroll
  for (int e = 0; e < 8; ++e) {
    u32 kk = keys[i0 + e];
    bool in = (kk > t) || (kk == t && (exc + seen) < kth);
    if (kk == t) ++seen;
    myb |= (in ? 1u : 0u) << e;
  }
  ((unsigned char*)mbw)[tid] = myb;
  __syncthreads();
  if (tid < 32) dst[tid] = mbw[tid];
}

// ---------------- Stage 2: swapped-QK flash attention with k-split + 5 blocks/CU ----------------
// LDS exactly 32 KiB (Ks+Vt; slash mask read per-lane from L1 global) -> 5 resident
// blocks/CU; grid 1536 (LPT split units) provides backfill. s_setprio around MFMA clusters.
template <bool PRE>
__global__ __launch_bounds__(256, 5) void attn_kernel(const float* __restrict__ q,
                                                      const float* __restrict__ kk,
                                                      const float* __restrict__ vv,
                                                      const u16* __restrict__ kpre,
                                                      const u16* __restrict__ vpre,
                                                      const u64* __restrict__ vbits,
                                                      const u64* __restrict__ sbits,
                                                      u16* __restrict__ p0,
                                                      float* __restrict__ mlb,
                                                      int split,
                                                      float* __restrict__ out) {
  int bid = blockIdx.x;
  int h, qt, t0, t1, mode;
  if (split) {
    int rr = bid >> 3;
    h = (bid & 7) * 4 + (rr & 3);       // 4 heads per XCD (L2 locality)
    int g = rr >> 2;                     // 0..47, ascending = LPT (descending work)
    if (g < 32) {
      qt = 31 - (g >> 1);
      int ntq = qt + 1, tm = ntq >> 1;
      if ((g & 1) == 0) { mode = 1; t0 = 0;  t1 = tm;  }
      else              { mode = 2; t0 = tm; t1 = ntq; }
    } else {
      mode = 0; qt = 47 - g; t0 = 0; t1 = qt + 1;
    }
  } else {
    int u = bid & 255, s = bid >> 8;
    h = u & 31;
    int v_ = u >> 5;
    switch (s) {
      case 0: qt = v_; break;
      case 1: qt = 31 - v_; break;
      case 2: qt = v_ + 16; break;
      default: qt = 15 - v_; break;
    }
    mode = 0; t0 = 0; t1 = qt + 1;
  }
  int tid = threadIdx.x;
  int wave = tid >> 6, lane = tid & 63;
  int grp = lane >> 4, ln = lane & 15;

  __shared__ u16 Ks[8192];   // 16 KiB
  __shared__ u16 Vt[8192];   // 16 KiB  (total exactly 32 KiB -> 5 blocks/CU)

  const u64* sbg = sbits + h * 32;

  int q0w = qt * 64 + wave * 16;
  bf16x8 qf[4];
  const float* qrow = q + ((size_t)h * S_LEN + q0w + ln) * D_DIM;
#pragma unroll
  for (int ks = 0; ks < 4; ++ks) {
    const float* p = qrow + ks * 32 + grp * 8;
    float4 a = *(const float4*)p;
    float4 b = *(const float4*)(p + 4);
    bf16x8 f;
    f[0] = (short)f32_bf16(a.x * QSCALE); f[1] = (short)f32_bf16(a.y * QSCALE);
    f[2] = (short)f32_bf16(a.z * QSCALE); f[3] = (short)f32_bf16(a.w * QSCALE);
    f[4] = (short)f32_bf16(b.x * QSCALE); f[5] = (short)f32_bf16(b.y * QSCALE);
    f[6] = (short)f32_bf16(b.z * QSCALE); f[7] = (short)f32_bf16(b.w * QSCALE);
    qf[ks] = f;
  }
  f32x4 of[8];
#pragma unroll
  for (int i = 0; i < 8; ++i) of[i] = (f32x4){0.f, 0.f, 0.f, 0.f};
  float mr = -1e30f;
  float ls = 0.f;

  const int kb0 = (ln << 7) + (((0 + grp) ^ ln) << 3);
  const int kb1 = (ln << 7) + (((4 + grp) ^ ln) << 3);
  const int kb2 = (ln << 7) + (((8 + grp) ^ ln) << 3);
  const int kb3 = (ln << 7) + (((12 + grp) ^ ln) << 3);
  const int vb0 = (ln << 6) + (((0 + grp) ^ (ln & 7)) << 3);
  const int vb1 = (ln << 6) + (((4 + grp) ^ (ln & 7)) << 3);

  const u16* kp = kpre + (size_t)h * 262144;
  const u16* vp = vpre + (size_t)h * 262144;
  const float* kfb = kk + (size_t)h * S_LEN * D_DIM;
  const float* vfb = vv + (size_t)h * S_LEN * D_DIM;
  const u64* vwp = vbits + h * 32;
  int sb_lane = (lane & 48) + ((lane & 48) >> 2);

  auto dma_k = [&](int t) {
    const u16* ksrc = kp + (size_t)t * 8192;
#pragma unroll
    for (int i = 0; i < 4; ++i) {
      int chunk = wave * 4 + i;
      __builtin_amdgcn_global_load_lds(
          (const __attribute__((address_space(1))) u32*)(const void*)(ksrc + (size_t)(chunk * 64 + lane) * 8),
          (__attribute__((address_space(3))) u32*)(void*)(&Ks[chunk * 512]), 16, 0, 0);
    }
  };
  auto dma_v = [&](int t) {
    const u16* vsrc = vp + (size_t)t * 8192;
#pragma unroll
    for (int i = 0; i < 4; ++i) {
      int chunk = wave * 4 + i;
      __builtin_amdgcn_global_load_lds(
          (const __attribute__((address_space(1))) u32*)(const void*)(vsrc + (size_t)(chunk * 64 + lane) * 8),
          (__attribute__((address_space(3))) u32*)(void*)(&Vt[chunk * 512]), 16, 0, 0);
    }
  };

  if constexpr (PRE) { dma_k(t0); dma_v(t0); }
  __syncthreads();  // drains prologue DMA

  for (int t = t0; t < t1; ++t) {
    int c0 = t * 64;
    if constexpr (!PRE) {
      for (int i = tid; i < 512; i += 256) {
        int r = i >> 3, s2 = i & 7;
        const float* srcp = kfb + (size_t)(c0 + r) * D_DIM + s2 * 16;
        float4 f0 = *(const float4*)(srcp);
        float4 f1 = *(const float4*)(srcp + 4);
        float4 f2 = *(const float4*)(srcp + 8);
        float4 f3 = *(const float4*)(srcp + 12);
        bf16x8 t0v, t1v;
        t0v[0] = (short)f32_bf16(f0.x); t0v[1] = (short)f32_bf16(f0.y);
        t0v[2] = (short)f32_bf16(f0.z); t0v[3] = (short)f32_bf16(f0.w);
        t0v[4] = (short)f32_bf16(f1.x); t0v[5] = (short)f32_bf16(f1.y);
        t0v[6] = (short)f32_bf16(f1.z); t0v[7] = (short)f32_bf16(f1.w);
        t1v[0] = (short)f32_bf16(f2.x); t1v[1] = (short)f32_bf16(f2.y);
        t1v[2] = (short)f32_bf16(f2.z); t1v[3] = (short)f32_bf16(f2.w);
        t1v[4] = (short)f32_bf16(f3.x); t1v[5] = (short)f32_bf16(f3.y);
        t1v[6] = (short)f32_bf16(f3.z); t1v[7] = (short)f32_bf16(f3.w);
        int cb0 = s2 * 2, cb1 = s2 * 2 + 1;
        *(bf16x8*)&Ks[r * 128 + ((cb0 ^ (r & 15)) << 3)] = t0v;
        *(bf16x8*)&Ks[r * 128 + ((cb1 ^ (r & 15)) << 3)] = t1v;
      }
      for (int i = tid; i < 512; i += 256) {
        int r = i >> 3, s2 = i & 7;
        const float* srcp = vfb + (size_t)(c0 + r) * D_DIM + s2 * 16;
#pragma unroll
        for (int x = 0; x < 16; x += 4) {
          float4 f4 = *(const float4*)(srcp + x);
          int d0 = s2 * 16 + x;
          float vals[4] = {f4.x, f4.y, f4.z, f4.w};
#pragma unroll
          for (int y = 0; y < 4; ++y) {
            int d = d0 + y;
            Vt[d * 64 + (((r >> 3) ^ (d & 7)) << 3) + (r & 7)] = f32_bf16(vals[y]);
          }
        }
      }
      __syncthreads();
    }

    // ---- swapped QK^T ----
    f32x4 sfr[4];
    __builtin_amdgcn_s_setprio(1);
#pragma unroll
    for (int nb = 0; nb < 4; ++nb) {
      f32x4 acc = (f32x4){0.f, 0.f, 0.f, 0.f};
      acc = __builtin_amdgcn_mfma_f32_16x16x32_bf16(*(const bf16x8*)&Ks[kb0 + nb * 2048], qf[0], acc, 0, 0, 0);
      acc = __builtin_amdgcn_mfma_f32_16x16x32_bf16(*(const bf16x8*)&Ks[kb1 + nb * 2048], qf[1], acc, 0, 0, 0);
      acc = __builtin_amdgcn_mfma_f32_16x16x32_bf16(*(const bf16x8*)&Ks[kb2 + nb * 2048], qf[2], acc, 0, 0, 0);
      acc = __builtin_amdgcn_mfma_f32_16x16x32_bf16(*(const bf16x8*)&Ks[kb3 + nb * 2048], qf[3], acc, 0, 0, 0);
      sfr[nb] = acc;
    }
    __builtin_amdgcn_s_setprio(0);

    // ---- row max ----
    float tm = sfr[0][0];
#pragma unroll
    for (int nb = 0; nb < 4; ++nb)
#pragma unroll
      for (int jj = 0; jj < 4; ++jj) tm = fmaxf(tm, sfr[nb][jj]);
    tm = fmaxf(tm, __shfl_xor(tm, 16, 64));
    tm = fmaxf(tm, __shfl_xor(tm, 32, 64));

    // ---- deferred rescale (T13) ----
    if (__any(tm - mr > RESCALE_THR)) {
      float mn = fmaxf(mr, tm);
      float ex = __builtin_amdgcn_exp2f(mr - mn);
      mr = mn;
      ls *= ex;
      float e0 = __shfl(ex, sb_lane, 64);
      float e1 = __shfl(ex, sb_lane + 1, 64);
      float e2 = __shfl(ex, sb_lane + 2, 64);
      float e3 = __shfl(ex, sb_lane + 3, 64);
#pragma unroll
      for (int db = 0; db < 8; ++db) {
        of[db][0] *= e0; of[db][1] *= e1; of[db][2] *= e2; of[db][3] *= e3;
      }
    }

    // ---- mask + p = exp2 + pack ----
    int Cb = (q0w + ln) - c0 - (grp << 2);
    float rs = 0.f;
    u32 pkw[8];
    if (c0 >= q0w - 48) {
#pragma unroll
      for (int nb = 0; nb < 4; ++nb) {
        float pv[4];
#pragma unroll
        for (int jj = 0; jj < 4; ++jj) {
          bool keep = (16 * nb + jj) <= Cb;
          float p = keep ? __builtin_amdgcn_exp2f(sfr[nb][jj] - mr) : 0.f;
          rs += p;
          pv[jj] = p;
        }
        pkw[nb * 2] = cvt_pk_bf16(pv[0], pv[1]);
        pkw[nb * 2 + 1] = cvt_pk_bf16(pv[2], pv[3]);
      }
    } else {
      int b0 = Cb - 63;
      int si = b0 >> 6;       // [-1, 31]
      int sh = b0 & 63;
      u64 lo = (si >= 0) ? sbg[si] : 0ull;
      u64 hi = (si < 31) ? sbg[si + 1] : 0ull;
      u64 W = (sh == 0) ? lo : ((lo >> sh) | (hi << (64 - sh)));
      u64 vword = vwp[t];
#pragma unroll
      for (int nb = 0; nb < 4; ++nb) {
        u32 vn = (u32)(vword >> (16 * nb + 4 * grp)) & 0xFu;
        u32 sn = (u32)(W >> (60 - 16 * nb)) & 0xFu;
        float pv[4];
#pragma unroll
        for (int jj = 0; jj < 4; ++jj) {
          u32 keep = ((vn >> jj) | (sn >> (3 - jj))) & 1u;
          float p = keep ? __builtin_amdgcn_exp2f(sfr[nb][jj] - mr) : 0.f;
          rs += p;
          pv[jj] = p;
        }
        pkw[nb * 2] = cvt_pk_bf16(pv[0], pv[1]);
        pkw[nb * 2 + 1] = cvt_pk_bf16(pv[2], pv[3]);
      }
    }
    rs += __shfl_xor(rs, 16, 64);
    rs += __shfl_xor(rs, 32, 64);
    ls += rs;

    // ---- BAR_A: Ks reads done + V(t) visible; prefetch K(t+1) ----
    if constexpr (PRE) {
      __builtin_amdgcn_sched_barrier(0);
      asm volatile("s_waitcnt vmcnt(0)" ::: "memory");
      __builtin_amdgcn_s_barrier();
      if (t + 1 < t1) dma_k(t + 1);
    }

    // ---- PV ----
#pragma unroll
    for (int ks2 = 0; ks2 < 2; ++ks2) {
      int sl0 = ln + ((lane & 16) << 1);
      int sl1 = sl0 + 16;
      u32 a0 = __shfl(pkw[ks2 * 4 + 0], sl0, 64);
      u32 a1 = __shfl(pkw[ks2 * 4 + 1], sl0, 64);
      u32 a2 = __shfl(pkw[ks2 * 4 + 0], sl1, 64);
      u32 a3 = __shfl(pkw[ks2 * 4 + 1], sl1, 64);
      u32 b0_ = __shfl(pkw[ks2 * 4 + 2], sl0, 64);
      u32 b1_ = __shfl(pkw[ks2 * 4 + 3], sl0, 64);
      u32 b2_ = __shfl(pkw[ks2 * 4 + 2], sl1, 64);
      u32 b3_ = __shfl(pkw[ks2 * 4 + 3], sl1, 64);
      bool hi2 = grp >= 2;
      union { u32 w[4]; bf16x8 v; } pu;
      pu.w[0] = hi2 ? b0_ : a0;
      pu.w[1] = hi2 ? b1_ : a1;
      pu.w[2] = hi2 ? b2_ : a2;
      pu.w[3] = hi2 ? b3_ : a3;
      int vb = ks2 ? vb1 : vb0;
      __builtin_amdgcn_s_setprio(1);
#pragma unroll
      for (int db = 0; db < 8; ++db) {
        bf16x8 vf = *(const bf16x8*)&Vt[vb + db * 1024];
        of[db] = __builtin_amdgcn_mfma_f32_16x16x32_bf16(pu.v, vf, of[db], 0, 0, 0);
      }
      __builtin_amdgcn_s_setprio(0);
    }

    // ---- BAR_B: Vt reads done; prefetch V(t+1); wait K(t+1); BAR_C ----
    if constexpr (PRE) {
      __builtin_amdgcn_sched_barrier(0);
      __builtin_amdgcn_s_barrier();
      if (t + 1 < t1) {
        dma_v(t + 1);
        asm volatile("s_waitcnt vmcnt(4)" ::: "memory");
      }
      __builtin_amdgcn_s_barrier();
    } else {
      __syncthreads();
    }
  }

  // ---- epilogue ----
  if (mode == 0) {
    float invl = 1.f / ls;
    float i0 = __shfl(invl, sb_lane, 64);
    float i1 = __shfl(invl, sb_lane + 1, 64);
    float i2 = __shfl(invl, sb_lane + 2, 64);
    float i3 = __shfl(invl, sb_lane + 3, 64);
    float* ob = out + ((size_t)h * S_LEN + q0w) * D_DIM;
#pragma unroll
    for (int db = 0; db < 8; ++db) {
      ob[(size_t)(grp * 4 + 0) * D_DIM + db * 16 + ln] = of[db][0] * i0;
      ob[(size_t)(grp * 4 + 1) * D_DIM + db * 16 + ln] = of[db][1] * i1;
      ob[(size_t)(grp * 4 + 2) * D_DIM + db * 16 + ln] = of[db][2] * i2;
      ob[(size_t)(grp * 4 + 3) * D_DIM + db * 16 + ln] = of[db][3] * i3;
    }
  } else {
    int ro_base = q0w - 1024;  // rows in upper half
    if (mode == 2) {
      float* ob = out + ((size_t)h * S_LEN + q0w) * D_DIM;
#pragma unroll
      for (int db = 0; db < 8; ++db)
#pragma unroll
        for (int j = 0; j < 4; ++j)
          ob[(size_t)(grp * 4 + j) * D_DIM + db * 16 + ln] = of[db][j];
    } else {
      u16* pb = p0 + ((size_t)h * 1024 + ro_base) * D_DIM;
#pragma unroll
      for (int db = 0; db < 8; ++db)
#pragma unroll
        for (int j = 0; j < 4; ++j)
          pb[(size_t)(grp * 4 + j) * D_DIM + db * 16 + ln] = f32_bf16(of[db][j]);
    }
    if (lane < 16) {
      int ro = ro_base + ln;
      float* mb = mlb + (size_t)(mode - 1) * 65536;
      mb[h * 1024 + ro] = mr;
      mb[32768 + h * 1024 + ro] = ls;
    }
  }
}

// ---------------- Stage 3: combine H0 (bf16, ws) + H1 (f32, in out) -> final upper rows ----------------
__global__ __launch_bounds__(256) void combine_kernel(const u16* __restrict__ p0,
                                                      const float* __restrict__ mlb,
                                                      float* __restrict__ out) {
  int bid = blockIdx.x;          // 2048
  int h = bid >> 6, rg = bid & 63;
  int tid = threadIdx.x;
  int r = rg * 16 + (tid >> 4);  // [0,1024)
  int c = (tid & 15) * 8;
  int idx = h * 1024 + r;
  float M0 = mlb[idx],          L0 = mlb[32768 + idx];
  float M1 = mlb[65536 + idx],  L1 = mlb[98304 + idx];
  float M = fmaxf(M0, M1);
  float w0 = __builtin_amdgcn_exp2f(M0 - M);
  float w1 = __builtin_amdgcn_exp2f(M1 - M);
  float inv = 1.f / (L0 * w0 + L1 * w1);
  size_t po = ((size_t)h * 1024 + r) * 128 + c;
  size_t oo = ((size_t)h * 2048 + 1024 + r) * 128 + c;
  bf16x8 a = *(const bf16x8*)(p0 + po);
  float4 b0 = *(const float4*)(out + oo);
  float4 b1 = *(const float4*)(out + oo + 4);
  float bvals[8] = {b0.x, b0.y, b0.z, b0.w, b1.x, b1.y, b1.z, b1.w};
  float o[8];
#pragma unroll
  for (int e = 0; e < 8; ++e) {
    float av = __uint_as_float(((u32)(u16)a[e]) << 16);
    o[e] = (av * w0 + bvals[e] * w1) * inv;
  }
  *(float4*)(out + oo) = make_float4(o[0], o[1], o[2], o[3]);
  *(float4*)(out + oo + 4) = make_float4(o[4], o[5], o[6], o[7]);
}

extern "C" void kernel_launch(void* const* d_in, const int* in_sizes, int n_in,
                              void* d_out, int out_size, void* d_ws, size_t ws_size,
                              hipStream_t stream) {
  const float* q = (const float*)d_in[0];
  const float* k = (const float*)d_in[1];
  const float* v = (const float*)d_in[2];
  float* out = (float*)d_out;
  float* scores = out;                 // dead before attn writes begin
  float* part = out + 4194304;         // dead after topk
  u64* vbits = (u64*)d_ws;
  u64* sbits = vbits + 1024;
  const size_t PRE_NEED = 16384 + 2ull * 16777216;                  // masks + kpre + vpre
  const size_t SPLIT_NEED = PRE_NEED + 8388608 + 524288;            // + P0(bf16) + ml
  bool pre = ws_size >= PRE_NEED;
  bool split = ws_size >= SPLIT_NEED;
  u16* kpre = (u16*)((char*)d_ws + 16384);
  u16* vpre = kpre + 8388608;
  u16* p0 = (u16*)((char*)d_ws + PRE_NEED);
  float* mlb = (float*)((char*)d_ws + PRE_NEED + 8388608);

  if (pre) conv_kernel<<<1024, 256, 0, stream>>>(k, v, kpre, vpre);
  est_kernel<<<dim3(32, 32), 256, 0, stream>>>(q, k, scores);
  soft_partial_kernel<<<dim3(32, 16), 256, 0, stream>>>(scores, part);
  topk_kernel<<<dim3(32, 2), 256, 0, stream>>>(part, vbits, sbits);
  if (pre) {
    if (split) {
      attn_kernel<true><<<1536, 256, 0, stream>>>(q, k, v, kpre, vpre, vbits, sbits,
                                                  p0, mlb, 1, out);
      combine_kernel<<<2048, 256, 0, stream>>>(p0, mlb, out);
    } else {
      attn_kernel<true><<<1024, 256, 0, stream>>>(q, k, v, kpre, vpre, vbits, sbits,
                                                  p0, mlb, 0, out);
    }
  } else {
    attn_kernel<false><<<1024, 256, 0, stream>>>(q, k, v, kpre, vpre, vbits, sbits,
                                                 p0, mlb, 0, out);
  }
}

// Round 12
// 184.302 us; speedup vs baseline: 1.0382x; 1.0382x over previous
//
#include <hip/hip_runtime.h>
#include <hip/hip_bf16.h>

#define S_LEN 2048
#define NH 32
#define D_DIM 128
#define LAST_Q 64
#define SCALE_F 0.08838834764831845f
#define QSCALE (0.08838834764831845f * 1.4426950408889634f)  // scale * log2(e)
#define RESCALE_THR 11.54f

typedef __attribute__((ext_vector_type(8))) short bf16x8;
typedef __attribute__((ext_vector_type(4))) float f32x4;
typedef unsigned long long u64;
typedef unsigned int u32;
typedef unsigned short u16;

static __device__ __forceinline__ u16 f32_bf16(float f) {
  u32 u = __float_as_uint(f);
  u32 r = (u + 0x7FFFu + ((u >> 16) & 1u)) >> 16;
  return (u16)r;
}

static __device__ __forceinline__ u32 cvt_pk_bf16(float lo, float hi) {
  u32 r;
  asm("v_cvt_pk_bf16_f32 %0, %1, %2" : "=v"(r) : "v"(lo), "v"(hi));
  return r;
}

// ---------------- Stage 0: preconvert to PRE-SWIZZLED bf16 layouts (R7 verbatim) ----------------
__global__ __launch_bounds__(256) void conv_kernel(const float* __restrict__ k,
                                                   const float* __restrict__ v,
                                                   u16* __restrict__ kpre,
                                                   u16* __restrict__ vpre) {
  int bid = blockIdx.x;
  int t = bid & 31, h = bid >> 5;
  int tid = threadIdx.x;
  int c0 = t * 64;
  __shared__ u16 Vb[64][136];
  for (int i = tid; i < 512; i += 256) {
    int r = i >> 3, s = i & 7;
    const float* srcp = v + ((size_t)(h * S_LEN + c0 + r)) * D_DIM + s * 16;
    float4 f0 = *(const float4*)(srcp);
    float4 f1 = *(const float4*)(srcp + 4);
    float4 f2 = *(const float4*)(srcp + 8);
    float4 f3 = *(const float4*)(srcp + 12);
    bf16x8 t0, t1;
    t0[0] = (short)f32_bf16(f0.x); t0[1] = (short)f32_bf16(f0.y);
    t0[2] = (short)f32_bf16(f0.z); t0[3] = (short)f32_bf16(f0.w);
    t0[4] = (short)f32_bf16(f1.x); t0[5] = (short)f32_bf16(f1.y);
    t0[6] = (short)f32_bf16(f1.z); t0[7] = (short)f32_bf16(f1.w);
    t1[0] = (short)f32_bf16(f2.x); t1[1] = (short)f32_bf16(f2.y);
    t1[2] = (short)f32_bf16(f2.z); t1[3] = (short)f32_bf16(f2.w);
    t1[4] = (short)f32_bf16(f3.x); t1[5] = (short)f32_bf16(f3.y);
    t1[6] = (short)f32_bf16(f3.z); t1[7] = (short)f32_bf16(f3.w);
    *(bf16x8*)&Vb[r][s * 16] = t0;
    *(bf16x8*)&Vb[r][s * 16 + 8] = t1;
  }
  u16* kp = kpre + (size_t)h * 262144 + (size_t)t * 8192;
#pragma unroll
  for (int j = 0; j < 4; ++j) {
    int p = j * 256 + tid;
    int r = p >> 4;
    int g = (p & 15) ^ (r & 15);
    const float* srcp = k + ((size_t)(h * S_LEN + c0 + r)) * D_DIM + g * 8;
    float4 a = *(const float4*)srcp;
    float4 b = *(const float4*)(srcp + 4);
    bf16x8 o;
    o[0] = (short)f32_bf16(a.x); o[1] = (short)f32_bf16(a.y);
    o[2] = (short)f32_bf16(a.z); o[3] = (short)f32_bf16(a.w);
    o[4] = (short)f32_bf16(b.x); o[5] = (short)f32_bf16(b.y);
    o[6] = (short)f32_bf16(b.z); o[7] = (short)f32_bf16(b.w);
    *(bf16x8*)(kp + p * 8) = o;
  }
  __syncthreads();
  u16* vp = vpre + (size_t)h * 262144 + (size_t)t * 8192;
#pragma unroll
  for (int j = 0; j < 4; ++j) {
    int p = j * 256 + tid;
    int d = p >> 3;
    int cb = (p & 7) ^ (d & 7);
    bf16x8 g;
#pragma unroll
    for (int e = 0; e < 8; ++e) g[e] = (short)Vb[cb * 8 + e][d];
    *(bf16x8*)(vp + p * 8) = g;
  }
}

// ---------------- Stage 1a: est scores (f32 VALU — selection-stable) ----------------
__global__ __launch_bounds__(256) void est_kernel(const float* __restrict__ q,
                                                  const float* __restrict__ k,
                                                  float* __restrict__ scores) {
  int cc = blockIdx.x;
  int h = blockIdx.y;
  int tid = threadIdx.x;
  int ty = tid >> 4, tx = tid & 15;
  __shared__ float Qs[64][36];
  __shared__ float Ks[64][36];
  float acc[4][4];
#pragma unroll
  for (int i = 0; i < 4; ++i)
#pragma unroll
    for (int j = 0; j < 4; ++j) acc[i][j] = 0.f;
  const float* qbase = q + ((size_t)h * S_LEN + (S_LEN - LAST_Q)) * D_DIM;
  const float* kbase = k + ((size_t)h * S_LEN + cc * 64) * D_DIM;
  for (int dc = 0; dc < 4; ++dc) {
    __syncthreads();
    for (int i = tid; i < 512; i += 256) {
      int r = i >> 3, s = i & 7;
      float4 a = *(const float4*)(qbase + (size_t)r * D_DIM + dc * 32 + s * 4);
      *(float4*)&Qs[r][s * 4] = a;
      float4 b = *(const float4*)(kbase + (size_t)r * D_DIM + dc * 32 + s * 4);
      *(float4*)&Ks[r][s * 4] = b;
    }
    __syncthreads();
#pragma unroll
    for (int d4 = 0; d4 < 8; ++d4) {
      float4 qv[4], kv[4];
#pragma unroll
      for (int i = 0; i < 4; ++i) qv[i] = *(const float4*)&Qs[ty + 16 * i][d4 * 4];
#pragma unroll
      for (int j = 0; j < 4; ++j) kv[j] = *(const float4*)&Ks[tx + 16 * j][d4 * 4];
#pragma unroll
      for (int i = 0; i < 4; ++i)
#pragma unroll
        for (int j = 0; j < 4; ++j)
          acc[i][j] += qv[i].x * kv[j].x + qv[i].y * kv[j].y + qv[i].z * kv[j].z + qv[i].w * kv[j].w;
    }
  }
#pragma unroll
  for (int i = 0; i < 4; ++i) {
    int rl = ty + 16 * i;
    int rg = (S_LEN - LAST_Q) + rl;
#pragma unroll
    for (int j = 0; j < 4; ++j) {
      int cg = cc * 64 + tx + 16 * j;
      float vv = (cg <= rg) ? acc[i][j] * SCALE_F : -1e30f;
      scores[((size_t)h * LAST_Q + rl) * S_LEN + cg] = vv;
    }
  }
}

// ---------------- Stage 1b: softmax partials (grid 32 x 16, 4 rows each) ----------------
__global__ __launch_bounds__(256) void soft_partial_kernel(const float* __restrict__ scores,
                                                           float* __restrict__ part) {
  int h = blockIdx.x, rg = blockIdx.y;
  int tid = threadIdx.x;
  int wave = tid >> 6, lane = tid & 63;
  __shared__ float vs[2048];
  __shared__ float ss[2048];
  __shared__ float red[4];
  int i0 = tid * 8;
#pragma unroll
  for (int e = 0; e < 8; ++e) { vs[i0 + e] = 0.f; ss[i0 + e] = 0.f; }
  for (int rr = 0; rr < 4; ++rr) {
    int r = rg * 4 + rr;
    const float* sp = scores + ((size_t)h * LAST_Q + r) * S_LEN;
    float4 a = *(const float4*)(sp + i0);
    float4 b = *(const float4*)(sp + i0 + 4);
    float x[8] = {a.x, a.y, a.z, a.w, b.x, b.y, b.z, b.w};
    float wm = -1e30f;
#pragma unroll
    for (int e = 0; e < 8; ++e) wm = fmaxf(wm, x[e]);
#pragma unroll
    for (int mk = 1; mk < 64; mk <<= 1) wm = fmaxf(wm, __shfl_xor(wm, mk, 64));
    __syncthreads();
    if (lane == 0) red[wave] = wm;
    __syncthreads();
    float m = fmaxf(fmaxf(red[0], red[1]), fmaxf(red[2], red[3]));
    float psum = 0.f;
#pragma unroll
    for (int e = 0; e < 8; ++e) { x[e] = __expf(x[e] - m); psum += x[e]; }
#pragma unroll
    for (int mk = 1; mk < 64; mk <<= 1) psum += __shfl_xor(psum, mk, 64);
    __syncthreads();
    if (lane == 0) red[wave] = psum;
    __syncthreads();
    float inv = 1.f / (red[0] + red[1] + red[2] + red[3]);
    int rgl = (S_LEN - LAST_Q) + r;
#pragma unroll
    for (int e = 0; e < 8; ++e) {
      float p = x[e] * inv;
      int i = i0 + e;
      vs[i] += p;
      int d = rgl - i;
      if (d >= 0) ss[d] += p;
    }
  }
  __syncthreads();
  float* pb = part + ((size_t)(h * 16 + rg)) * 4096;
#pragma unroll
  for (int e = 0; e < 8; ++e) { pb[i0 + e] = vs[i0 + e]; pb[2048 + i0 + e] = ss[i0 + e]; }
}

// ---------------- Stage 1c: fused reduce + top-k -> bitmasks ----------------
__global__ __launch_bounds__(256) void topk_kernel(const float* __restrict__ part,
                                                   u64* __restrict__ vbits,
                                                   u64* __restrict__ sbits) {
  int h = blockIdx.x;
  int which = blockIdx.y;
  u64* dst = which ? (sbits + h * 32) : (vbits + h * 32);
  u32 K = which ? 512u : 256u;
  int ninf = which ? 64 : 4;
  int tid = threadIdx.x;
  int lane = tid & 63, wid = tid >> 6;
  __shared__ u32 keys[2048];
  __shared__ u32 hist[256];
  __shared__ u32 wpart[4];
  __shared__ u32 sh_pref, sh_kth;
  __shared__ u64 mbw[32];
  int i0 = tid * 8;
  float accv[8] = {0.f, 0.f, 0.f, 0.f, 0.f, 0.f, 0.f, 0.f};
  for (int rg = 0; rg < 16; ++rg) {
    const float* pp = part + ((size_t)(h * 16 + rg)) * 4096 + which * 2048 + i0;
    float4 a = *(const float4*)pp;
    float4 b = *(const float4*)(pp + 4);
    accv[0] += a.x; accv[1] += a.y; accv[2] += a.z; accv[3] += a.w;
    accv[4] += b.x; accv[5] += b.y; accv[6] += b.z; accv[7] += b.w;
  }
#pragma unroll
  for (int e = 0; e < 8; ++e) {
    int i = i0 + e;
    keys[i] = (i < ninf) ? 0x7F800000u : __float_as_uint(accv[e]);
  }
  __syncthreads();
  u32 prefix = 0;
  u32 kth = K;
  for (int shift = 24; shift >= 0; shift -= 8) {
    hist[tid] = 0;
    __syncthreads();
#pragma unroll
    for (int e = 0; e < 8; ++e) {
      u32 kk = keys[i0 + e];
      if (shift == 24 || (kk >> (shift + 8)) == (prefix >> (shift + 8)))
        atomicAdd(&hist[(kk >> shift) & 255], 1u);
    }
    __syncthreads();
    u32 v = hist[tid];
    u32 x = v;
#pragma unroll
    for (int off = 1; off < 64; off <<= 1) {
      u32 o = __shfl_up(x, off, 64);
      if (lane >= off) x += o;
    }
    if (lane == 63) wpart[wid] = x;
    __syncthreads();
    u32 base = 0;
    for (int w2 = 0; w2 < wid; ++w2) base += wpart[w2];
    u32 T = wpart[0] + wpart[1] + wpart[2] + wpart[3];
    u32 Pincl = x + base;
    u32 Sb = T - Pincl + v;
    u32 Sn = T - Pincl;
    if (Sb >= kth && Sn < kth) {
      sh_pref = prefix | ((u32)tid << shift);
      sh_kth = kth - Sn;
    }
    __syncthreads();
    prefix = sh_pref;
    kth = sh_kth;
    __syncthreads();
  }
  u32 t = prefix;
  u32 cnt = 0;
#pragma unroll
  for (int e = 0; e < 8; ++e) cnt += (keys[i0 + e] == t) ? 1u : 0u;
  u32 x = cnt;
#pragma unroll
  for (int off = 1; off < 64; off <<= 1) {
    u32 o = __shfl_up(x, off, 64);
    if (lane >= off) x += o;
  }
  if (lane == 63) wpart[wid] = x;
  __syncthreads();
  u32 base = 0;
  for (int w2 = 0; w2 < wid; ++w2) base += wpart[w2];
  u32 exc = x + base - cnt;
  unsigned char myb = 0;
  u32 seen = 0;
#pragma unroll
  for (int e = 0; e < 8; ++e) {
    u32 kk = keys[i0 + e];
    bool in = (kk > t) || (kk == t && (exc + seen) < kth);
    if (kk == t) ++seen;
    myb |= (in ? 1u : 0u) << e;
  }
  ((unsigned char*)mbw)[tid] = myb;
  __syncthreads();
  if (tid < 32) dst[tid] = mbw[tid];
}

// ---------------- Stage 2: swapped-QK flash attention, k-split + 5 blocks/CU ----------------
// LDS exactly 32 KiB (Ks+Vt). Slash table lives IN REGISTERS: 64 u32 distributed one per
// lane; per-tile window via 3 ds_bpermute shuffles + funnel shift (no LDS, no VMEM).
template <bool PRE>
__global__ __launch_bounds__(256, 5) void attn_kernel(const float* __restrict__ q,
                                                      const float* __restrict__ kk,
                                                      const float* __restrict__ vv,
                                                      const u16* __restrict__ kpre,
                                                      const u16* __restrict__ vpre,
                                                      const u64* __restrict__ vbits,
                                                      const u64* __restrict__ sbits,
                                                      u16* __restrict__ p0,
                                                      float* __restrict__ mlb,
                                                      int split,
                                                      float* __restrict__ out) {
  int bid = blockIdx.x;
  int h, qt, t0, t1, mode;
  if (split) {
    int rr = bid >> 3;
    h = (bid & 7) * 4 + (rr & 3);       // 4 heads per XCD (L2 locality)
    int g = rr >> 2;                     // 0..47, ascending = LPT (descending work)
    if (g < 32) {
      qt = 31 - (g >> 1);
      int ntq = qt + 1, tm = ntq >> 1;
      if ((g & 1) == 0) { mode = 1; t0 = 0;  t1 = tm;  }
      else              { mode = 2; t0 = tm; t1 = ntq; }
    } else {
      mode = 0; qt = 47 - g; t0 = 0; t1 = qt + 1;
    }
  } else {
    int u = bid & 255, s = bid >> 8;
    h = u & 31;
    int v_ = u >> 5;
    switch (s) {
      case 0: qt = v_; break;
      case 1: qt = 31 - v_; break;
      case 2: qt = v_ + 16; break;
      default: qt = 15 - v_; break;
    }
    mode = 0; t0 = 0; t1 = qt + 1;
  }
  int tid = threadIdx.x;
  int wave = tid >> 6, lane = tid & 63;
  int grp = lane >> 4, ln = lane & 15;

  __shared__ u16 Ks[8192];   // 16 KiB
  __shared__ u16 Vt[8192];   // 16 KiB  (total exactly 32 KiB -> 5 blocks/CU)

  // register-resident slash table: lane l holds u32 word l (64 words = 2048 bits)
  const u32* sb32 = (const u32*)(sbits + h * 32);
  u32 smpv = sb32[lane];

  int q0w = qt * 64 + wave * 16;
  bf16x8 qf[4];
  const float* qrow = q + ((size_t)h * S_LEN + q0w + ln) * D_DIM;
#pragma unroll
  for (int ks = 0; ks < 4; ++ks) {
    const float* p = qrow + ks * 32 + grp * 8;
    float4 a = *(const float4*)p;
    float4 b = *(const float4*)(p + 4);
    bf16x8 f;
    f[0] = (short)f32_bf16(a.x * QSCALE); f[1] = (short)f32_bf16(a.y * QSCALE);
    f[2] = (short)f32_bf16(a.z * QSCALE); f[3] = (short)f32_bf16(a.w * QSCALE);
    f[4] = (short)f32_bf16(b.x * QSCALE); f[5] = (short)f32_bf16(b.y * QSCALE);
    f[6] = (short)f32_bf16(b.z * QSCALE); f[7] = (short)f32_bf16(b.w * QSCALE);
    qf[ks] = f;
  }
  f32x4 of[8];
#pragma unroll
  for (int i = 0; i < 8; ++i) of[i] = (f32x4){0.f, 0.f, 0.f, 0.f};
  float mr = -1e30f;
  float ls = 0.f;

  const int kb0 = (ln << 7) + (((0 + grp) ^ ln) << 3);
  const int kb1 = (ln << 7) + (((4 + grp) ^ ln) << 3);
  const int kb2 = (ln << 7) + (((8 + grp) ^ ln) << 3);
  const int kb3 = (ln << 7) + (((12 + grp) ^ ln) << 3);
  const int vb0 = (ln << 6) + (((0 + grp) ^ (ln & 7)) << 3);
  const int vb1 = (ln << 6) + (((4 + grp) ^ (ln & 7)) << 3);

  const u16* kp = kpre + (size_t)h * 262144;
  const u16* vp = vpre + (size_t)h * 262144;
  const float* kfb = kk + (size_t)h * S_LEN * D_DIM;
  const float* vfb = vv + (size_t)h * S_LEN * D_DIM;
  const u64* vwp = vbits + h * 32;
  int sb_lane = (lane & 48) + ((lane & 48) >> 2);

  auto dma_k = [&](int t) {
    const u16* ksrc = kp + (size_t)t * 8192;
#pragma unroll
    for (int i = 0; i < 4; ++i) {
      int chunk = wave * 4 + i;
      __builtin_amdgcn_global_load_lds(
          (const __attribute__((address_space(1))) u32*)(const void*)(ksrc + (size_t)(chunk * 64 + lane) * 8),
          (__attribute__((address_space(3))) u32*)(void*)(&Ks[chunk * 512]), 16, 0, 0);
    }
  };
  auto dma_v = [&](int t) {
    const u16* vsrc = vp + (size_t)t * 8192;
#pragma unroll
    for (int i = 0; i < 4; ++i) {
      int chunk = wave * 4 + i;
      __builtin_amdgcn_global_load_lds(
          (const __attribute__((address_space(1))) u32*)(const void*)(vsrc + (size_t)(chunk * 64 + lane) * 8),
          (__attribute__((address_space(3))) u32*)(void*)(&Vt[chunk * 512]), 16, 0, 0);
    }
  };

  if constexpr (PRE) { dma_k(t0); dma_v(t0); }
  __syncthreads();  // drains prologue DMA

  for (int t = t0; t < t1; ++t) {
    int c0 = t * 64;
    if constexpr (!PRE) {
      for (int i = tid; i < 512; i += 256) {
        int r = i >> 3, s2 = i & 7;
        const float* srcp = kfb + (size_t)(c0 + r) * D_DIM + s2 * 16;
        float4 f0 = *(const float4*)(srcp);
        float4 f1 = *(const float4*)(srcp + 4);
        float4 f2 = *(const float4*)(srcp + 8);
        float4 f3 = *(const float4*)(srcp + 12);
        bf16x8 t0v, t1v;
        t0v[0] = (short)f32_bf16(f0.x); t0v[1] = (short)f32_bf16(f0.y);
        t0v[2] = (short)f32_bf16(f0.z); t0v[3] = (short)f32_bf16(f0.w);
        t0v[4] = (short)f32_bf16(f1.x); t0v[5] = (short)f32_bf16(f1.y);
        t0v[6] = (short)f32_bf16(f1.z); t0v[7] = (short)f32_bf16(f1.w);
        t1v[0] = (short)f32_bf16(f2.x); t1v[1] = (short)f32_bf16(f2.y);
        t1v[2] = (short)f32_bf16(f2.z); t1v[3] = (short)f32_bf16(f2.w);
        t1v[4] = (short)f32_bf16(f3.x); t1v[5] = (short)f32_bf16(f3.y);
        t1v[6] = (short)f32_bf16(f3.z); t1v[7] = (short)f32_bf16(f3.w);
        int cb0 = s2 * 2, cb1 = s2 * 2 + 1;
        *(bf16x8*)&Ks[r * 128 + ((cb0 ^ (r & 15)) << 3)] = t0v;
        *(bf16x8*)&Ks[r * 128 + ((cb1 ^ (r & 15)) << 3)] = t1v;
      }
      for (int i = tid; i < 512; i += 256) {
        int r = i >> 3, s2 = i & 7;
        const float* srcp = vfb + (size_t)(c0 + r) * D_DIM + s2 * 16;
#pragma unroll
        for (int x = 0; x < 16; x += 4) {
          float4 f4 = *(const float4*)(srcp + x);
          int d0 = s2 * 16 + x;
          float vals[4] = {f4.x, f4.y, f4.z, f4.w};
#pragma unroll
          for (int y = 0; y < 4; ++y) {
            int d = d0 + y;
            Vt[d * 64 + (((r >> 3) ^ (d & 7)) << 3) + (r & 7)] = f32_bf16(vals[y]);
          }
        }
      }
      __syncthreads();
    }

    // ---- swapped QK^T ----
    f32x4 sfr[4];
#pragma unroll
    for (int nb = 0; nb < 4; ++nb) {
      f32x4 acc = (f32x4){0.f, 0.f, 0.f, 0.f};
      acc = __builtin_amdgcn_mfma_f32_16x16x32_bf16(*(const bf16x8*)&Ks[kb0 + nb * 2048], qf[0], acc, 0, 0, 0);
      acc = __builtin_amdgcn_mfma_f32_16x16x32_bf16(*(const bf16x8*)&Ks[kb1 + nb * 2048], qf[1], acc, 0, 0, 0);
      acc = __builtin_amdgcn_mfma_f32_16x16x32_bf16(*(const bf16x8*)&Ks[kb2 + nb * 2048], qf[2], acc, 0, 0, 0);
      acc = __builtin_amdgcn_mfma_f32_16x16x32_bf16(*(const bf16x8*)&Ks[kb3 + nb * 2048], qf[3], acc, 0, 0, 0);
      sfr[nb] = acc;
    }

    // ---- row max ----
    float tm = sfr[0][0];
#pragma unroll
    for (int nb = 0; nb < 4; ++nb)
#pragma unroll
      for (int jj = 0; jj < 4; ++jj) tm = fmaxf(tm, sfr[nb][jj]);
    tm = fmaxf(tm, __shfl_xor(tm, 16, 64));
    tm = fmaxf(tm, __shfl_xor(tm, 32, 64));

    // ---- deferred rescale (T13) ----
    if (__any(tm - mr > RESCALE_THR)) {
      float mn = fmaxf(mr, tm);
      float ex = __builtin_amdgcn_exp2f(mr - mn);
      mr = mn;
      ls *= ex;
      float e0 = __shfl(ex, sb_lane, 64);
      float e1 = __shfl(ex, sb_lane + 1, 64);
      float e2 = __shfl(ex, sb_lane + 2, 64);
      float e3 = __shfl(ex, sb_lane + 3, 64);
#pragma unroll
      for (int db = 0; db < 8; ++db) {
        of[db][0] *= e0; of[db][1] *= e1; of[db][2] *= e2; of[db][3] *= e3;
      }
    }

    // ---- mask + p = exp2 + pack ----
    int Cb = (q0w + ln) - c0 - (grp << 2);
    float rs = 0.f;
    u32 pkw[8];
    if (c0 >= q0w - 48) {
#pragma unroll
      for (int nb = 0; nb < 4; ++nb) {
        float pv[4];
#pragma unroll
        for (int jj = 0; jj < 4; ++jj) {
          bool keep = (16 * nb + jj) <= Cb;
          float p = keep ? __builtin_amdgcn_exp2f(sfr[nb][jj] - mr) : 0.f;
          rs += p;
          pv[jj] = p;
        }
        pkw[nb * 2] = cvt_pk_bf16(pv[0], pv[1]);
        pkw[nb * 2 + 1] = cvt_pk_bf16(pv[2], pv[3]);
      }
    } else {
      // W[j] = slash-bit(b0 + j), from register table via 3 dynamic shuffles + funnel
      int b0 = Cb - 63;
      int widx = b0 >> 5;       // [-1, 62]
      int sh5 = b0 & 31;
      u32 x0 = __shfl(smpv, widx & 63, 64);
      u32 x1 = __shfl(smpv, (widx + 1) & 63, 64);
      u32 x2 = __shfl(smpv, (widx + 2) & 63, 64);
      x0 = (widx >= 0) ? x0 : 0u;
      x2 = (widx + 2 < 64) ? x2 : 0u;
      u64 loP = (u64)x0 | ((u64)x1 << 32);
      u64 W = (sh5 == 0) ? loP : ((loP >> sh5) | ((u64)x2 << (64 - sh5)));
      u64 vword = vwp[t];
#pragma unroll
      for (int nb = 0; nb < 4; ++nb) {
        u32 vn = (u32)(vword >> (16 * nb + 4 * grp)) & 0xFu;
        u32 sn = (u32)(W >> (60 - 16 * nb)) & 0xFu;
        float pv[4];
#pragma unroll
        for (int jj = 0; jj < 4; ++jj) {
          u32 keep = ((vn >> jj) | (sn >> (3 - jj))) & 1u;
          float p = keep ? __builtin_amdgcn_exp2f(sfr[nb][jj] - mr) : 0.f;
          rs += p;
          pv[jj] = p;
        }
        pkw[nb * 2] = cvt_pk_bf16(pv[0], pv[1]);
        pkw[nb * 2 + 1] = cvt_pk_bf16(pv[2], pv[3]);
      }
    }
    rs += __shfl_xor(rs, 16, 64);
    rs += __shfl_xor(rs, 32, 64);
    ls += rs;

    // ---- BAR_A: Ks reads done + V(t) visible; prefetch K(t+1) ----
    if constexpr (PRE) {
      __builtin_amdgcn_sched_barrier(0);
      asm volatile("s_waitcnt vmcnt(0)" ::: "memory");
      __builtin_amdgcn_s_barrier();
      if (t + 1 < t1) dma_k(t + 1);
    }

    // ---- PV ----
#pragma unroll
    for (int ks2 = 0; ks2 < 2; ++ks2) {
      int sl0 = ln + ((lane & 16) << 1);
      int sl1 = sl0 + 16;
      u32 a0 = __shfl(pkw[ks2 * 4 + 0], sl0, 64);
      u32 a1 = __shfl(pkw[ks2 * 4 + 1], sl0, 64);
      u32 a2 = __shfl(pkw[ks2 * 4 + 0], sl1, 64);
      u32 a3 = __shfl(pkw[ks2 * 4 + 1], sl1, 64);
      u32 b0_ = __shfl(pkw[ks2 * 4 + 2], sl0, 64);
      u32 b1_ = __shfl(pkw[ks2 * 4 + 3], sl0, 64);
      u32 b2_ = __shfl(pkw[ks2 * 4 + 2], sl1, 64);
      u32 b3_ = __shfl(pkw[ks2 * 4 + 3], sl1, 64);
      bool hi2 = grp >= 2;
      union { u32 w[4]; bf16x8 v; } pu;
      pu.w[0] = hi2 ? b0_ : a0;
      pu.w[1] = hi2 ? b1_ : a1;
      pu.w[2] = hi2 ? b2_ : a2;
      pu.w[3] = hi2 ? b3_ : a3;
      int vb = ks2 ? vb1 : vb0;
#pragma unroll
      for (int db = 0; db < 8; ++db) {
        bf16x8 vf = *(const bf16x8*)&Vt[vb + db * 1024];
        of[db] = __builtin_amdgcn_mfma_f32_16x16x32_bf16(pu.v, vf, of[db], 0, 0, 0);
      }
    }

    // ---- BAR_B: Vt reads done; prefetch V(t+1); wait K(t+1); BAR_C ----
    if constexpr (PRE) {
      __builtin_amdgcn_sched_barrier(0);
      __builtin_amdgcn_s_barrier();
      if (t + 1 < t1) {
        dma_v(t + 1);
        asm volatile("s_waitcnt vmcnt(4)" ::: "memory");
      }
      __builtin_amdgcn_s_barrier();
    } else {
      __syncthreads();
    }
  }

  // ---- epilogue ----
  if (mode == 0) {
    float invl = 1.f / ls;
    float i0 = __shfl(invl, sb_lane, 64);
    float i1 = __shfl(invl, sb_lane + 1, 64);
    float i2 = __shfl(invl, sb_lane + 2, 64);
    float i3 = __shfl(invl, sb_lane + 3, 64);
    float* ob = out + ((size_t)h * S_LEN + q0w) * D_DIM;
#pragma unroll
    for (int db = 0; db < 8; ++db) {
      ob[(size_t)(grp * 4 + 0) * D_DIM + db * 16 + ln] = of[db][0] * i0;
      ob[(size_t)(grp * 4 + 1) * D_DIM + db * 16 + ln] = of[db][1] * i1;
      ob[(size_t)(grp * 4 + 2) * D_DIM + db * 16 + ln] = of[db][2] * i2;
      ob[(size_t)(grp * 4 + 3) * D_DIM + db * 16 + ln] = of[db][3] * i3;
    }
  } else {
    int ro_base = q0w - 1024;  // rows in upper half
    if (mode == 2) {
      float* ob = out + ((size_t)h * S_LEN + q0w) * D_DIM;
#pragma unroll
      for (int db = 0; db < 8; ++db)
#pragma unroll
        for (int j = 0; j < 4; ++j)
          ob[(size_t)(grp * 4 + j) * D_DIM + db * 16 + ln] = of[db][j];
    } else {
      u16* pb = p0 + ((size_t)h * 1024 + ro_base) * D_DIM;
#pragma unroll
      for (int db = 0; db < 8; ++db)
#pragma unroll
        for (int j = 0; j < 4; ++j)
          pb[(size_t)(grp * 4 + j) * D_DIM + db * 16 + ln] = f32_bf16(of[db][j]);
    }
    if (lane < 16) {
      int ro = ro_base + ln;
      float* mb = mlb + (size_t)(mode - 1) * 65536;
      mb[h * 1024 + ro] = mr;
      mb[32768 + h * 1024 + ro] = ls;
    }
  }
}

// ---------------- Stage 3: combine H0 (bf16, ws) + H1 (f32, in out) -> final upper rows ----------------
__global__ __launch_bounds__(256) void combine_kernel(const u16* __restrict__ p0,
                                                      const float* __restrict__ mlb,
                                                      float* __restrict__ out) {
  int bid = blockIdx.x;          // 2048
  int h = bid >> 6, rg = bid & 63;
  int tid = threadIdx.x;
  int r = rg * 16 + (tid >> 4);  // [0,1024)
  int c = (tid & 15) * 8;
  int idx = h * 1024 + r;
  float M0 = mlb[idx],          L0 = mlb[32768 + idx];
  float M1 = mlb[65536 + idx],  L1 = mlb[98304 + idx];
  float M = fmaxf(M0, M1);
  float w0 = __builtin_amdgcn_exp2f(M0 - M);
  float w1 = __builtin_amdgcn_exp2f(M1 - M);
  float inv = 1.f / (L0 * w0 + L1 * w1);
  size_t po = ((size_t)h * 1024 + r) * 128 + c;
  size_t oo = ((size_t)h * 2048 + 1024 + r) * 128 + c;
  bf16x8 a = *(const bf16x8*)(p0 + po);
  float4 b0 = *(const float4*)(out + oo);
  float4 b1 = *(const float4*)(out + oo + 4);
  float bvals[8] = {b0.x, b0.y, b0.z, b0.w, b1.x, b1.y, b1.z, b1.w};
  float o[8];
#pragma unroll
  for (int e = 0; e < 8; ++e) {
    float av = __uint_as_float(((u32)(u16)a[e]) << 16);
    o[e] = (av * w0 + bvals[e] * w1) * inv;
  }
  *(float4*)(out + oo) = make_float4(o[0], o[1], o[2], o[3]);
  *(float4*)(out + oo + 4) = make_float4(o[4], o[5], o[6], o[7]);
}

extern "C" void kernel_launch(void* const* d_in, const int* in_sizes, int n_in,
                              void* d_out, int out_size, void* d_ws, size_t ws_size,
                              hipStream_t stream) {
  const float* q = (const float*)d_in[0];
  const float* k = (const float*)d_in[1];
  const float* v = (const float*)d_in[2];
  float* out = (float*)d_out;
  float* scores = out;                 // dead before attn writes begin
  float* part = out + 4194304;         // dead after topk
  u64* vbits = (u64*)d_ws;
  u64* sbits = vbits + 1024;
  const size_t PRE_NEED = 16384 + 2ull * 16777216;                  // masks + kpre + vpre
  const size_t SPLIT_NEED = PRE_NEED + 8388608 + 524288;            // + P0(bf16) + ml
  bool pre = ws_size >= PRE_NEED;
  bool split = ws_size >= SPLIT_NEED;
  u16* kpre = (u16*)((char*)d_ws + 16384);
  u16* vpre = kpre + 8388608;
  u16* p0 = (u16*)((char*)d_ws + PRE_NEED);
  float* mlb = (float*)((char*)d_ws + PRE_NEED + 8388608);

  if (pre) conv_kernel<<<1024, 256, 0, stream>>>(k, v, kpre, vpre);
  est_kernel<<<dim3(32, 32), 256, 0, stream>>>(q, k, scores);
  soft_partial_kernel<<<dim3(32, 16), 256, 0, stream>>>(scores, part);
  topk_kernel<<<dim3(32, 2), 256, 0, stream>>>(part, vbits, sbits);
  if (pre) {
    if (split) {
      attn_kernel<true><<<1536, 256, 0, stream>>>(q, k, v, kpre, vpre, vbits, sbits,
                                                  p0, mlb, 1, out);
      combine_kernel<<<2048, 256, 0, stream>>>(p0, mlb, out);
    } else {
      attn_kernel<true><<<1024, 256, 0, stream>>>(q, k, v, kpre, vpre, vbits, sbits,
                                                  p0, mlb, 0, out);
    }
  } else {
    attn_kernel<false><<<1024, 256, 0, stream>>>(q, k, v, kpre, vpre, vbits, sbits,
                                                 p0, mlb, 0, out);
  }
}

// Round 13
// 154.897 us; speedup vs baseline: 1.2353x; 1.1898x over previous
//
#include <hip/hip_runtime.h>
#include <hip/hip_bf16.h>

#define S_LEN 2048
#define NH 32
#define D_DIM 128
#define LAST_Q 64
#define SCALE_F 0.08838834764831845f
#define QSCALE (0.08838834764831845f * 1.4426950408889634f)  // scale * log2(e)
#define RESCALE_THR 11.54f

typedef __attribute__((ext_vector_type(8))) short bf16x8;
typedef __attribute__((ext_vector_type(4))) float f32x4;
typedef unsigned long long u64;
typedef unsigned int u32;
typedef unsigned short u16;

static __device__ __forceinline__ u16 f32_bf16(float f) {
  u32 u = __float_as_uint(f);
  u32 r = (u + 0x7FFFu + ((u >> 16) & 1u)) >> 16;
  return (u16)r;
}

static __device__ __forceinline__ u32 cvt_pk_bf16(float lo, float hi) {
  u32 r;
  asm("v_cvt_pk_bf16_f32 %0, %1, %2" : "=v"(r) : "v"(lo), "v"(hi));
  return r;
}

// Balanced per-CU-class unit table: 8 groups x 6 units. Each group = 4 halves (j=0..3,
// co-resident) + 2 wholes (j=4..5, backfill); every group sums to exactly 66 tiles.
// entry = qt | (kind<<8); kind: 0=whole, 1=first-half [0,tm), 2=second-half [tm,nt).
__device__ __constant__ u16 unit_tab[48] = {
  (31|(1<<8)),(30|(1<<8)),(20|(1<<8)),(16|(1<<8)),(15       ),(0        ),
  (31|(2<<8)),(29|(1<<8)),(18|(1<<8)),(17|(1<<8)),(14       ),(1        ),
  (30|(2<<8)),(28|(1<<8)),(19|(1<<8)),(17|(2<<8)),(13       ),(2        ),
  (29|(2<<8)),(27|(1<<8)),(22|(1<<8)),(16|(2<<8)),(12       ),(3        ),
  (28|(2<<8)),(27|(2<<8)),(19|(2<<8)),(18|(2<<8)),(11       ),(4        ),
  (26|(2<<8)),(26|(1<<8)),(21|(1<<8)),(21|(2<<8)),(10       ),(5        ),
  (25|(1<<8)),(25|(2<<8)),(23|(1<<8)),(20|(2<<8)),(9        ),(6        ),
  (24|(2<<8)),(24|(1<<8)),(23|(2<<8)),(22|(2<<8)),(8        ),(7        ),
};

// ---------------- Stage 0: preconvert to PRE-SWIZZLED bf16 layouts (R7 verbatim) ----------------
__global__ __launch_bounds__(256) void conv_kernel(const float* __restrict__ k,
                                                   const float* __restrict__ v,
                                                   u16* __restrict__ kpre,
                                                   u16* __restrict__ vpre) {
  int bid = blockIdx.x;
  int t = bid & 31, h = bid >> 5;
  int tid = threadIdx.x;
  int c0 = t * 64;
  __shared__ u16 Vb[64][136];
  for (int i = tid; i < 512; i += 256) {
    int r = i >> 3, s = i & 7;
    const float* srcp = v + ((size_t)(h * S_LEN + c0 + r)) * D_DIM + s * 16;
    float4 f0 = *(const float4*)(srcp);
    float4 f1 = *(const float4*)(srcp + 4);
    float4 f2 = *(const float4*)(srcp + 8);
    float4 f3 = *(const float4*)(srcp + 12);
    bf16x8 t0, t1;
    t0[0] = (short)f32_bf16(f0.x); t0[1] = (short)f32_bf16(f0.y);
    t0[2] = (short)f32_bf16(f0.z); t0[3] = (short)f32_bf16(f0.w);
    t0[4] = (short)f32_bf16(f1.x); t0[5] = (short)f32_bf16(f1.y);
    t0[6] = (short)f32_bf16(f1.z); t0[7] = (short)f32_bf16(f1.w);
    t1[0] = (short)f32_bf16(f2.x); t1[1] = (short)f32_bf16(f2.y);
    t1[2] = (short)f32_bf16(f2.z); t1[3] = (short)f32_bf16(f2.w);
    t1[4] = (short)f32_bf16(f3.x); t1[5] = (short)f32_bf16(f3.y);
    t1[6] = (short)f32_bf16(f3.z); t1[7] = (short)f32_bf16(f3.w);
    *(bf16x8*)&Vb[r][s * 16] = t0;
    *(bf16x8*)&Vb[r][s * 16 + 8] = t1;
  }
  u16* kp = kpre + (size_t)h * 262144 + (size_t)t * 8192;
#pragma unroll
  for (int j = 0; j < 4; ++j) {
    int p = j * 256 + tid;
    int r = p >> 4;
    int g = (p & 15) ^ (r & 15);
    const float* srcp = k + ((size_t)(h * S_LEN + c0 + r)) * D_DIM + g * 8;
    float4 a = *(const float4*)srcp;
    float4 b = *(const float4*)(srcp + 4);
    bf16x8 o;
    o[0] = (short)f32_bf16(a.x); o[1] = (short)f32_bf16(a.y);
    o[2] = (short)f32_bf16(a.z); o[3] = (short)f32_bf16(a.w);
    o[4] = (short)f32_bf16(b.x); o[5] = (short)f32_bf16(b.y);
    o[6] = (short)f32_bf16(b.z); o[7] = (short)f32_bf16(b.w);
    *(bf16x8*)(kp + p * 8) = o;
  }
  __syncthreads();
  u16* vp = vpre + (size_t)h * 262144 + (size_t)t * 8192;
#pragma unroll
  for (int j = 0; j < 4; ++j) {
    int p = j * 256 + tid;
    int d = p >> 3;
    int cb = (p & 7) ^ (d & 7);
    bf16x8 g;
#pragma unroll
    for (int e = 0; e < 8; ++e) g[e] = (short)Vb[cb * 8 + e][d];
    *(bf16x8*)(vp + p * 8) = g;
  }
}

// ---------------- Stage 1a: est scores (f32 VALU — selection-stable) ----------------
__global__ __launch_bounds__(256) void est_kernel(const float* __restrict__ q,
                                                  const float* __restrict__ k,
                                                  float* __restrict__ scores) {
  int cc = blockIdx.x;
  int h = blockIdx.y;
  int tid = threadIdx.x;
  int ty = tid >> 4, tx = tid & 15;
  __shared__ float Qs[64][36];
  __shared__ float Ks[64][36];
  float acc[4][4];
#pragma unroll
  for (int i = 0; i < 4; ++i)
#pragma unroll
    for (int j = 0; j < 4; ++j) acc[i][j] = 0.f;
  const float* qbase = q + ((size_t)h * S_LEN + (S_LEN - LAST_Q)) * D_DIM;
  const float* kbase = k + ((size_t)h * S_LEN + cc * 64) * D_DIM;
  for (int dc = 0; dc < 4; ++dc) {
    __syncthreads();
    for (int i = tid; i < 512; i += 256) {
      int r = i >> 3, s = i & 7;
      float4 a = *(const float4*)(qbase + (size_t)r * D_DIM + dc * 32 + s * 4);
      *(float4*)&Qs[r][s * 4] = a;
      float4 b = *(const float4*)(kbase + (size_t)r * D_DIM + dc * 32 + s * 4);
      *(float4*)&Ks[r][s * 4] = b;
    }
    __syncthreads();
#pragma unroll
    for (int d4 = 0; d4 < 8; ++d4) {
      float4 qv[4], kv[4];
#pragma unroll
      for (int i = 0; i < 4; ++i) qv[i] = *(const float4*)&Qs[ty + 16 * i][d4 * 4];
#pragma unroll
      for (int j = 0; j < 4; ++j) kv[j] = *(const float4*)&Ks[tx + 16 * j][d4 * 4];
#pragma unroll
      for (int i = 0; i < 4; ++i)
#pragma unroll
        for (int j = 0; j < 4; ++j)
          acc[i][j] += qv[i].x * kv[j].x + qv[i].y * kv[j].y + qv[i].z * kv[j].z + qv[i].w * kv[j].w;
    }
  }
#pragma unroll
  for (int i = 0; i < 4; ++i) {
    int rl = ty + 16 * i;
    int rg = (S_LEN - LAST_Q) + rl;
#pragma unroll
    for (int j = 0; j < 4; ++j) {
      int cg = cc * 64 + tx + 16 * j;
      float vv = (cg <= rg) ? acc[i][j] * SCALE_F : -1e30f;
      scores[((size_t)h * LAST_Q + rl) * S_LEN + cg] = vv;
    }
  }
}

// ---------------- Stage 1b: softmax partials (R7 version: grid 32 x 8, 8 rows) ----------------
__global__ __launch_bounds__(256) void soft_partial_kernel(const float* __restrict__ scores,
                                                           float* __restrict__ part) {
  int h = blockIdx.x, rg = blockIdx.y;
  int tid = threadIdx.x;
  int wave = tid >> 6, lane = tid & 63;
  __shared__ float vs[2048];
  __shared__ float ss[2048];
  __shared__ float red[4];
  int i0 = tid * 8;
#pragma unroll
  for (int e = 0; e < 8; ++e) { vs[i0 + e] = 0.f; ss[i0 + e] = 0.f; }
  for (int rr = 0; rr < 8; ++rr) {
    int r = rg * 8 + rr;
    const float* sp = scores + ((size_t)h * LAST_Q + r) * S_LEN;
    float4 a = *(const float4*)(sp + i0);
    float4 b = *(const float4*)(sp + i0 + 4);
    float x[8] = {a.x, a.y, a.z, a.w, b.x, b.y, b.z, b.w};
    float wm = -1e30f;
#pragma unroll
    for (int e = 0; e < 8; ++e) wm = fmaxf(wm, x[e]);
#pragma unroll
    for (int mk = 1; mk < 64; mk <<= 1) wm = fmaxf(wm, __shfl_xor(wm, mk, 64));
    __syncthreads();
    if (lane == 0) red[wave] = wm;
    __syncthreads();
    float m = fmaxf(fmaxf(red[0], red[1]), fmaxf(red[2], red[3]));
    float psum = 0.f;
#pragma unroll
    for (int e = 0; e < 8; ++e) { x[e] = __expf(x[e] - m); psum += x[e]; }
#pragma unroll
    for (int mk = 1; mk < 64; mk <<= 1) psum += __shfl_xor(psum, mk, 64);
    __syncthreads();
    if (lane == 0) red[wave] = psum;
    __syncthreads();
    float inv = 1.f / (red[0] + red[1] + red[2] + red[3]);
    int rgl = (S_LEN - LAST_Q) + r;
#pragma unroll
    for (int e = 0; e < 8; ++e) {
      float p = x[e] * inv;
      int i = i0 + e;
      vs[i] += p;
      int d = rgl - i;
      if (d >= 0) ss[d] += p;
    }
  }
  __syncthreads();
  float* pb = part + ((size_t)(h * 8 + rg)) * 4096;
#pragma unroll
  for (int e = 0; e < 8; ++e) { pb[i0 + e] = vs[i0 + e]; pb[2048 + i0 + e] = ss[i0 + e]; }
}

// ---------------- Stage 1c: fused reduce + top-k -> bitmasks (R7 version) ----------------
__global__ __launch_bounds__(256) void topk_kernel(const float* __restrict__ part,
                                                   u64* __restrict__ vbits,
                                                   u64* __restrict__ sbits) {
  int h = blockIdx.x;
  int which = blockIdx.y;
  u64* dst = which ? (sbits + h * 32) : (vbits + h * 32);
  u32 K = which ? 512u : 256u;
  int ninf = which ? 64 : 4;
  int tid = threadIdx.x;
  int lane = tid & 63, wid = tid >> 6;
  __shared__ u32 keys[2048];
  __shared__ u32 hist[256];
  __shared__ u32 wpart[4];
  __shared__ u32 sh_pref, sh_kth;
  __shared__ u64 mbw[32];
  int i0 = tid * 8;
  float accv[8] = {0.f, 0.f, 0.f, 0.f, 0.f, 0.f, 0.f, 0.f};
  for (int rg = 0; rg < 8; ++rg) {
    const float* pp = part + ((size_t)(h * 8 + rg)) * 4096 + which * 2048 + i0;
    float4 a = *(const float4*)pp;
    float4 b = *(const float4*)(pp + 4);
    accv[0] += a.x; accv[1] += a.y; accv[2] += a.z; accv[3] += a.w;
    accv[4] += b.x; accv[5] += b.y; accv[6] += b.z; accv[7] += b.w;
  }
#pragma unroll
  for (int e = 0; e < 8; ++e) {
    int i = i0 + e;
    keys[i] = (i < ninf) ? 0x7F800000u : __float_as_uint(accv[e]);
  }
  __syncthreads();
  u32 prefix = 0;
  u32 kth = K;
  for (int shift = 24; shift >= 0; shift -= 8) {
    hist[tid] = 0;
    __syncthreads();
#pragma unroll
    for (int e = 0; e < 8; ++e) {
      u32 kk = keys[i0 + e];
      if (shift == 24 || (kk >> (shift + 8)) == (prefix >> (shift + 8)))
        atomicAdd(&hist[(kk >> shift) & 255], 1u);
    }
    __syncthreads();
    u32 v = hist[tid];
    u32 x = v;
#pragma unroll
    for (int off = 1; off < 64; off <<= 1) {
      u32 o = __shfl_up(x, off, 64);
      if (lane >= off) x += o;
    }
    if (lane == 63) wpart[wid] = x;
    __syncthreads();
    u32 base = 0;
    for (int w2 = 0; w2 < wid; ++w2) base += wpart[w2];
    u32 T = wpart[0] + wpart[1] + wpart[2] + wpart[3];
    u32 Pincl = x + base;
    u32 Sb = T - Pincl + v;
    u32 Sn = T - Pincl;
    if (Sb >= kth && Sn < kth) {
      sh_pref = prefix | ((u32)tid << shift);
      sh_kth = kth - Sn;
    }
    __syncthreads();
    prefix = sh_pref;
    kth = sh_kth;
    __syncthreads();
  }
  u32 t = prefix;
  u32 cnt = 0;
#pragma unroll
  for (int e = 0; e < 8; ++e) cnt += (keys[i0 + e] == t) ? 1u : 0u;
  u32 x = cnt;
#pragma unroll
  for (int off = 1; off < 64; off <<= 1) {
    u32 o = __shfl_up(x, off, 64);
    if (lane >= off) x += o;
  }
  if (lane == 63) wpart[wid] = x;
  __syncthreads();
  u32 base = 0;
  for (int w2 = 0; w2 < wid; ++w2) base += wpart[w2];
  u32 exc = x + base - cnt;
  unsigned char myb = 0;
  u32 seen = 0;
#pragma unroll
  for (int e = 0; e < 8; ++e) {
    u32 kk = keys[i0 + e];
    bool in = (kk > t) || (kk == t && (exc + seen) < kth);
    if (kk == t) ++seen;
    myb |= (in ? 1u : 0u) << e;
  }
  ((unsigned char*)mbw)[tid] = myb;
  __syncthreads();
  if (tid < 32) dst[tid] = mbw[tid];
}

// ---------------- Stage 2: swapped-QK flash attention, balanced split units ----------------
// split=1: grid 1536. Class m=bid&255 -> (h = m&31, group r = m>>5); j = bid>>8 selects
// one of the group's 6 units from unit_tab (4 halves co-resident + 2 whole backfills;
// every class sums to 66 tiles, makespan <= 22 vs R7's 32). split=0: R7 whole-block map.
template <bool PRE>
__global__ __launch_bounds__(256, 4) void attn_kernel(const float* __restrict__ q,
                                                      const float* __restrict__ kk,
                                                      const float* __restrict__ vv,
                                                      const u16* __restrict__ kpre,
                                                      const u16* __restrict__ vpre,
                                                      const u64* __restrict__ vbits,
                                                      const u64* __restrict__ sbits,
                                                      u16* __restrict__ p0,
                                                      float* __restrict__ mlb,
                                                      int split,
                                                      float* __restrict__ out) {
  int bid = blockIdx.x;
  int h, qt, t0, t1, mode;
  if (split) {
    int m = bid & 255, j = bid >> 8;
    h = m & 31;
    int r = m >> 5;
    u32 e = unit_tab[r * 6 + j];
    qt = (int)(e & 255u);
    int kind = (int)(e >> 8);
    int ntq = qt + 1, tm = ntq >> 1;
    if (kind == 0)      { mode = 0; t0 = 0;  t1 = ntq; }
    else if (kind == 1) { mode = 1; t0 = 0;  t1 = tm;  }
    else                { mode = 2; t0 = tm; t1 = ntq; }
  } else {
    int u = bid & 255, s = bid >> 8;
    h = u & 31;
    int v_ = u >> 5;
    switch (s) {
      case 0: qt = v_; break;
      case 1: qt = 31 - v_; break;
      case 2: qt = v_ + 16; break;
      default: qt = 15 - v_; break;
    }
    mode = 0; t0 = 0; t1 = qt + 1;
  }
  int tid = threadIdx.x;
  int wave = tid >> 6, lane = tid & 63;
  int grp = lane >> 4, ln = lane & 15;

  __shared__ u16 Ks[8192];
  __shared__ u16 Vt[8192];
  __shared__ u64 smp[34];

  if (tid < 34) smp[tid] = (tid == 0 || tid == 33) ? 0ull : sbits[h * 32 + tid - 1];

  int q0w = qt * 64 + wave * 16;
  bf16x8 qf[4];
  const float* qrow = q + ((size_t)h * S_LEN + q0w + ln) * D_DIM;
#pragma unroll
  for (int ks = 0; ks < 4; ++ks) {
    const float* p = qrow + ks * 32 + grp * 8;
    float4 a = *(const float4*)p;
    float4 b = *(const float4*)(p + 4);
    bf16x8 f;
    f[0] = (short)f32_bf16(a.x * QSCALE); f[1] = (short)f32_bf16(a.y * QSCALE);
    f[2] = (short)f32_bf16(a.z * QSCALE); f[3] = (short)f32_bf16(a.w * QSCALE);
    f[4] = (short)f32_bf16(b.x * QSCALE); f[5] = (short)f32_bf16(b.y * QSCALE);
    f[6] = (short)f32_bf16(b.z * QSCALE); f[7] = (short)f32_bf16(b.w * QSCALE);
    qf[ks] = f;
  }
  f32x4 of[8];
#pragma unroll
  for (int i = 0; i < 8; ++i) of[i] = (f32x4){0.f, 0.f, 0.f, 0.f};
  float mr = -1e30f;
  float ls = 0.f;

  const int kb0 = (ln << 7) + (((0 + grp) ^ ln) << 3);
  const int kb1 = (ln << 7) + (((4 + grp) ^ ln) << 3);
  const int kb2 = (ln << 7) + (((8 + grp) ^ ln) << 3);
  const int kb3 = (ln << 7) + (((12 + grp) ^ ln) << 3);
  const int vb0 = (ln << 6) + (((0 + grp) ^ (ln & 7)) << 3);
  const int vb1 = (ln << 6) + (((4 + grp) ^ (ln & 7)) << 3);

  const u16* kp = kpre + (size_t)h * 262144;
  const u16* vp = vpre + (size_t)h * 262144;
  const float* kfb = kk + (size_t)h * S_LEN * D_DIM;
  const float* vfb = vv + (size_t)h * S_LEN * D_DIM;
  const u64* vwp = vbits + h * 32;
  int sb_lane = (lane & 48) + ((lane & 48) >> 2);

  auto dma_k = [&](int t) {
    const u16* ksrc = kp + (size_t)t * 8192;
#pragma unroll
    for (int i = 0; i < 4; ++i) {
      int chunk = wave * 4 + i;
      __builtin_amdgcn_global_load_lds(
          (const __attribute__((address_space(1))) u32*)(const void*)(ksrc + (size_t)(chunk * 64 + lane) * 8),
          (__attribute__((address_space(3))) u32*)(void*)(&Ks[chunk * 512]), 16, 0, 0);
    }
  };
  auto dma_v = [&](int t) {
    const u16* vsrc = vp + (size_t)t * 8192;
#pragma unroll
    for (int i = 0; i < 4; ++i) {
      int chunk = wave * 4 + i;
      __builtin_amdgcn_global_load_lds(
          (const __attribute__((address_space(1))) u32*)(const void*)(vsrc + (size_t)(chunk * 64 + lane) * 8),
          (__attribute__((address_space(3))) u32*)(void*)(&Vt[chunk * 512]), 16, 0, 0);
    }
  };

  if constexpr (PRE) { dma_k(t0); dma_v(t0); }
  __syncthreads();  // drains prologue DMA + smp writes

  for (int t = t0; t < t1; ++t) {
    int c0 = t * 64;
    if constexpr (!PRE) {
      for (int i = tid; i < 512; i += 256) {
        int r = i >> 3, s2 = i & 7;
        const float* srcp = kfb + (size_t)(c0 + r) * D_DIM + s2 * 16;
        float4 f0 = *(const float4*)(srcp);
        float4 f1 = *(const float4*)(srcp + 4);
        float4 f2 = *(const float4*)(srcp + 8);
        float4 f3 = *(const float4*)(srcp + 12);
        bf16x8 t0v, t1v;
        t0v[0] = (short)f32_bf16(f0.x); t0v[1] = (short)f32_bf16(f0.y);
        t0v[2] = (short)f32_bf16(f0.z); t0v[3] = (short)f32_bf16(f0.w);
        t0v[4] = (short)f32_bf16(f1.x); t0v[5] = (short)f32_bf16(f1.y);
        t0v[6] = (short)f32_bf16(f1.z); t0v[7] = (short)f32_bf16(f1.w);
        t1v[0] = (short)f32_bf16(f2.x); t1v[1] = (short)f32_bf16(f2.y);
        t1v[2] = (short)f32_bf16(f2.z); t1v[3] = (short)f32_bf16(f2.w);
        t1v[4] = (short)f32_bf16(f3.x); t1v[5] = (short)f32_bf16(f3.y);
        t1v[6] = (short)f32_bf16(f3.z); t1v[7] = (short)f32_bf16(f3.w);
        int cb0 = s2 * 2, cb1 = s2 * 2 + 1;
        *(bf16x8*)&Ks[r * 128 + ((cb0 ^ (r & 15)) << 3)] = t0v;
        *(bf16x8*)&Ks[r * 128 + ((cb1 ^ (r & 15)) << 3)] = t1v;
      }
      for (int i = tid; i < 512; i += 256) {
        int r = i >> 3, s2 = i & 7;
        const float* srcp = vfb + (size_t)(c0 + r) * D_DIM + s2 * 16;
#pragma unroll
        for (int x = 0; x < 16; x += 4) {
          float4 f4 = *(const float4*)(srcp + x);
          int d0 = s2 * 16 + x;
          float vals[4] = {f4.x, f4.y, f4.z, f4.w};
#pragma unroll
          for (int y = 0; y < 4; ++y) {
            int d = d0 + y;
            Vt[d * 64 + (((r >> 3) ^ (d & 7)) << 3) + (r & 7)] = f32_bf16(vals[y]);
          }
        }
      }
      __syncthreads();
    }

    // ---- swapped QK^T ----
    f32x4 sfr[4];
#pragma unroll
    for (int nb = 0; nb < 4; ++nb) {
      f32x4 acc = (f32x4){0.f, 0.f, 0.f, 0.f};
      acc = __builtin_amdgcn_mfma_f32_16x16x32_bf16(*(const bf16x8*)&Ks[kb0 + nb * 2048], qf[0], acc, 0, 0, 0);
      acc = __builtin_amdgcn_mfma_f32_16x16x32_bf16(*(const bf16x8*)&Ks[kb1 + nb * 2048], qf[1], acc, 0, 0, 0);
      acc = __builtin_amdgcn_mfma_f32_16x16x32_bf16(*(const bf16x8*)&Ks[kb2 + nb * 2048], qf[2], acc, 0, 0, 0);
      acc = __builtin_amdgcn_mfma_f32_16x16x32_bf16(*(const bf16x8*)&Ks[kb3 + nb * 2048], qf[3], acc, 0, 0, 0);
      sfr[nb] = acc;
    }

    // ---- row max ----
    float tm2 = sfr[0][0];
#pragma unroll
    for (int nb = 0; nb < 4; ++nb)
#pragma unroll
      for (int jj = 0; jj < 4; ++jj) tm2 = fmaxf(tm2, sfr[nb][jj]);
    tm2 = fmaxf(tm2, __shfl_xor(tm2, 16, 64));
    tm2 = fmaxf(tm2, __shfl_xor(tm2, 32, 64));

    // ---- deferred rescale (T13) ----
    if (__any(tm2 - mr > RESCALE_THR)) {
      float mn = fmaxf(mr, tm2);
      float ex = __builtin_amdgcn_exp2f(mr - mn);
      mr = mn;
      ls *= ex;
      float e0 = __shfl(ex, sb_lane, 64);
      float e1 = __shfl(ex, sb_lane + 1, 64);
      float e2 = __shfl(ex, sb_lane + 2, 64);
      float e3 = __shfl(ex, sb_lane + 3, 64);
#pragma unroll
      for (int db = 0; db < 8; ++db) {
        of[db][0] *= e0; of[db][1] *= e1; of[db][2] *= e2; of[db][3] *= e3;
      }
    }

    // ---- mask + p = exp2 + pack ----
    int Cb = (q0w + ln) - c0 - (grp << 2);
    float rs = 0.f;
    u32 pkw[8];
    if (c0 >= q0w - 48) {
#pragma unroll
      for (int nb = 0; nb < 4; ++nb) {
        float pv[4];
#pragma unroll
        for (int jj = 0; jj < 4; ++jj) {
          bool keep = (16 * nb + jj) <= Cb;
          float p = keep ? __builtin_amdgcn_exp2f(sfr[nb][jj] - mr) : 0.f;
          rs += p;
          pv[jj] = p;
        }
        pkw[nb * 2] = cvt_pk_bf16(pv[0], pv[1]);
        pkw[nb * 2 + 1] = cvt_pk_bf16(pv[2], pv[3]);
      }
    } else {
      int b0 = Cb - 63;
      int w0i = (b0 >> 6) + 1;
      int sh = b0 & 63;
      u64 lo = smp[w0i];
      u64 hi = smp[w0i + 1];
      u64 W = (sh == 0) ? lo : ((lo >> sh) | (hi << (64 - sh)));
      u64 vword = vwp[t];
#pragma unroll
      for (int nb = 0; nb < 4; ++nb) {
        u32 vn = (u32)(vword >> (16 * nb + 4 * grp)) & 0xFu;
        u32 sn = (u32)(W >> (60 - 16 * nb)) & 0xFu;
        float pv[4];
#pragma unroll
        for (int jj = 0; jj < 4; ++jj) {
          u32 keep = ((vn >> jj) | (sn >> (3 - jj))) & 1u;
          float p = keep ? __builtin_amdgcn_exp2f(sfr[nb][jj] - mr) : 0.f;
          rs += p;
          pv[jj] = p;
        }
        pkw[nb * 2] = cvt_pk_bf16(pv[0], pv[1]);
        pkw[nb * 2 + 1] = cvt_pk_bf16(pv[2], pv[3]);
      }
    }
    rs += __shfl_xor(rs, 16, 64);
    rs += __shfl_xor(rs, 32, 64);
    ls += rs;

    // ---- BAR_A: Ks reads done + V(t) visible; prefetch K(t+1) ----
    if constexpr (PRE) {
      __builtin_amdgcn_sched_barrier(0);
      asm volatile("s_waitcnt vmcnt(0)" ::: "memory");
      __builtin_amdgcn_s_barrier();
      if (t + 1 < t1) dma_k(t + 1);
    }

    // ---- PV ----
#pragma unroll
    for (int ks2 = 0; ks2 < 2; ++ks2) {
      int sl0 = ln + ((lane & 16) << 1);
      int sl1 = sl0 + 16;
      u32 a0 = __shfl(pkw[ks2 * 4 + 0], sl0, 64);
      u32 a1 = __shfl(pkw[ks2 * 4 + 1], sl0, 64);
      u32 a2 = __shfl(pkw[ks2 * 4 + 0], sl1, 64);
      u32 a3 = __shfl(pkw[ks2 * 4 + 1], sl1, 64);
      u32 b0_ = __shfl(pkw[ks2 * 4 + 2], sl0, 64);
      u32 b1_ = __shfl(pkw[ks2 * 4 + 3], sl0, 64);
      u32 b2_ = __shfl(pkw[ks2 * 4 + 2], sl1, 64);
      u32 b3_ = __shfl(pkw[ks2 * 4 + 3], sl1, 64);
      bool hi2 = grp >= 2;
      union { u32 w[4]; bf16x8 v; } pu;
      pu.w[0] = hi2 ? b0_ : a0;
      pu.w[1] = hi2 ? b1_ : a1;
      pu.w[2] = hi2 ? b2_ : a2;
      pu.w[3] = hi2 ? b3_ : a3;
      int vb = ks2 ? vb1 : vb0;
#pragma unroll
      for (int db = 0; db < 8; ++db) {
        bf16x8 vf = *(const bf16x8*)&Vt[vb + db * 1024];
        of[db] = __builtin_amdgcn_mfma_f32_16x16x32_bf16(pu.v, vf, of[db], 0, 0, 0);
      }
    }

    // ---- BAR_B: Vt reads done; prefetch V(t+1); wait K(t+1); BAR_C ----
    if constexpr (PRE) {
      __builtin_amdgcn_sched_barrier(0);
      __builtin_amdgcn_s_barrier();
      if (t + 1 < t1) {
        dma_v(t + 1);
        asm volatile("s_waitcnt vmcnt(4)" ::: "memory");
      }
      __builtin_amdgcn_s_barrier();
    } else {
      __syncthreads();
    }
  }

  // ---- epilogue ----
  if (mode == 0) {
    float invl = 1.f / ls;
    float i0 = __shfl(invl, sb_lane, 64);
    float i1 = __shfl(invl, sb_lane + 1, 64);
    float i2 = __shfl(invl, sb_lane + 2, 64);
    float i3 = __shfl(invl, sb_lane + 3, 64);
    float* ob = out + ((size_t)h * S_LEN + q0w) * D_DIM;
#pragma unroll
    for (int db = 0; db < 8; ++db) {
      ob[(size_t)(grp * 4 + 0) * D_DIM + db * 16 + ln] = of[db][0] * i0;
      ob[(size_t)(grp * 4 + 1) * D_DIM + db * 16 + ln] = of[db][1] * i1;
      ob[(size_t)(grp * 4 + 2) * D_DIM + db * 16 + ln] = of[db][2] * i2;
      ob[(size_t)(grp * 4 + 3) * D_DIM + db * 16 + ln] = of[db][3] * i3;
    }
  } else {
    int ro_base = q0w - 1024;  // rows in upper half
    if (mode == 2) {
      float* ob = out + ((size_t)h * S_LEN + q0w) * D_DIM;
#pragma unroll
      for (int db = 0; db < 8; ++db)
#pragma unroll
        for (int j = 0; j < 4; ++j)
          ob[(size_t)(grp * 4 + j) * D_DIM + db * 16 + ln] = of[db][j];
    } else {
      u16* pb = p0 + ((size_t)h * 1024 + ro_base) * D_DIM;
#pragma unroll
      for (int db = 0; db < 8; ++db)
#pragma unroll
        for (int j = 0; j < 4; ++j)
          pb[(size_t)(grp * 4 + j) * D_DIM + db * 16 + ln] = f32_bf16(of[db][j]);
    }
    if (lane < 16) {
      int ro = ro_base + ln;
      float* mb = mlb + (size_t)(mode - 1) * 65536;
      mb[h * 1024 + ro] = mr;
      mb[32768 + h * 1024 + ro] = ls;
    }
  }
}

// ---------------- Stage 3: combine H0 (bf16, ws) + H1 (f32, in out) -> final upper rows ----------------
__global__ __launch_bounds__(256) void combine_kernel(const u16* __restrict__ p0,
                                                      const float* __restrict__ mlb,
                                                      float* __restrict__ out) {
  int bid = blockIdx.x;          // 2048
  int h = bid >> 6, rg = bid & 63;
  int tid = threadIdx.x;
  int r = rg * 16 + (tid >> 4);  // [0,1024)
  int c = (tid & 15) * 8;
  int idx = h * 1024 + r;
  float M0 = mlb[idx],          L0 = mlb[32768 + idx];
  float M1 = mlb[65536 + idx],  L1 = mlb[98304 + idx];
  float M = fmaxf(M0, M1);
  float w0 = __builtin_amdgcn_exp2f(M0 - M);
  float w1 = __builtin_amdgcn_exp2f(M1 - M);
  float inv = 1.f / (L0 * w0 + L1 * w1);
  size_t po = ((size_t)h * 1024 + r) * 128 + c;
  size_t oo = ((size_t)h * 2048 + 1024 + r) * 128 + c;
  bf16x8 a = *(const bf16x8*)(p0 + po);
  float4 b0 = *(const float4*)(out + oo);
  float4 b1 = *(const float4*)(out + oo + 4);
  float bvals[8] = {b0.x, b0.y, b0.z, b0.w, b1.x, b1.y, b1.z, b1.w};
  float o[8];
#pragma unroll
  for (int e = 0; e < 8; ++e) {
    float av = __uint_as_float(((u32)(u16)a[e]) << 16);
    o[e] = (av * w0 + bvals[e] * w1) * inv;
  }
  *(float4*)(out + oo) = make_float4(o[0], o[1], o[2], o[3]);
  *(float4*)(out + oo + 4) = make_float4(o[4], o[5], o[6], o[7]);
}

extern "C" void kernel_launch(void* const* d_in, const int* in_sizes, int n_in,
                              void* d_out, int out_size, void* d_ws, size_t ws_size,
                              hipStream_t stream) {
  const float* q = (const float*)d_in[0];
  const float* k = (const float*)d_in[1];
  const float* v = (const float*)d_in[2];
  float* out = (float*)d_out;
  float* scores = out;                 // dead before attn writes begin
  float* part = out + 4194304;         // dead after topk
  u64* vbits = (u64*)d_ws;
  u64* sbits = vbits + 1024;
  const size_t PRE_NEED = 16384 + 2ull * 16777216;                  // masks + kpre + vpre
  const size_t SPLIT_NEED = PRE_NEED + 8388608 + 524288;            // + P0(bf16) + ml
  bool pre = ws_size >= PRE_NEED;
  bool split = ws_size >= SPLIT_NEED;
  u16* kpre = (u16*)((char*)d_ws + 16384);
  u16* vpre = kpre + 8388608;
  u16* p0 = (u16*)((char*)d_ws + PRE_NEED);
  float* mlb = (float*)((char*)d_ws + PRE_NEED + 8388608);

  if (pre) conv_kernel<<<1024, 256, 0, stream>>>(k, v, kpre, vpre);
  est_kernel<<<dim3(32, 32), 256, 0, stream>>>(q, k, scores);
  soft_partial_kernel<<<dim3(32, 8), 256, 0, stream>>>(scores, part);
  topk_kernel<<<dim3(32, 2), 256, 0, stream>>>(part, vbits, sbits);
  if (pre) {
    if (split) {
      attn_kernel<true><<<1536, 256, 0, stream>>>(q, k, v, kpre, vpre, vbits, sbits,
                                                  p0, mlb, 1, out);
      combine_kernel<<<2048, 256, 0, stream>>>(p0, mlb, out);
    } else {
      attn_kernel<true><<<1024, 256, 0, stream>>>(q, k, v, kpre, vpre, vbits, sbits,
                                                  p0, mlb, 0, out);
    }
  } else {
    attn_kernel<false><<<1024, 256, 0, stream>>>(q, k, v, kpre, vpre, vbits, sbits,
                                                 p0, mlb, 0, out);
  }
}

// Round 14
// 150.900 us; speedup vs baseline: 1.2680x; 1.0265x over previous
//
#include <hip/hip_runtime.h>
#include <hip/hip_bf16.h>

#define S_LEN 2048
#define NH 32
#define D_DIM 128
#define LAST_Q 64
#define SCALE_F 0.08838834764831845f
#define QSCALE (0.08838834764831845f * 1.4426950408889634f)  // scale * log2(e)
#define RESCALE_THR 11.54f

typedef __attribute__((ext_vector_type(8))) short bf16x8;
typedef __attribute__((ext_vector_type(4))) float f32x4;
typedef unsigned long long u64;
typedef unsigned int u32;
typedef unsigned short u16;

static __device__ __forceinline__ u16 f32_bf16(float f) {
  u32 u = __float_as_uint(f);
  u32 r = (u + 0x7FFFu + ((u >> 16) & 1u)) >> 16;
  return (u16)r;
}

static __device__ __forceinline__ u32 cvt_pk_bf16(float lo, float hi) {
  u32 r;
  asm("v_cvt_pk_bf16_f32 %0, %1, %2" : "=v"(r) : "v"(lo), "v"(hi));
  return r;
}

// ---------------- Stage 0: preconvert to PRE-SWIZZLED bf16 layouts (R7 verbatim) ----------------
__global__ __launch_bounds__(256) void conv_kernel(const float* __restrict__ k,
                                                   const float* __restrict__ v,
                                                   u16* __restrict__ kpre,
                                                   u16* __restrict__ vpre) {
  int bid = blockIdx.x;
  int t = bid & 31, h = bid >> 5;
  int tid = threadIdx.x;
  int c0 = t * 64;
  __shared__ u16 Vb[64][136];
  for (int i = tid; i < 512; i += 256) {
    int r = i >> 3, s = i & 7;
    const float* srcp = v + ((size_t)(h * S_LEN + c0 + r)) * D_DIM + s * 16;
    float4 f0 = *(const float4*)(srcp);
    float4 f1 = *(const float4*)(srcp + 4);
    float4 f2 = *(const float4*)(srcp + 8);
    float4 f3 = *(const float4*)(srcp + 12);
    bf16x8 t0, t1;
    t0[0] = (short)f32_bf16(f0.x); t0[1] = (short)f32_bf16(f0.y);
    t0[2] = (short)f32_bf16(f0.z); t0[3] = (short)f32_bf16(f0.w);
    t0[4] = (short)f32_bf16(f1.x); t0[5] = (short)f32_bf16(f1.y);
    t0[6] = (short)f32_bf16(f1.z); t0[7] = (short)f32_bf16(f1.w);
    t1[0] = (short)f32_bf16(f2.x); t1[1] = (short)f32_bf16(f2.y);
    t1[2] = (short)f32_bf16(f2.z); t1[3] = (short)f32_bf16(f2.w);
    t1[4] = (short)f32_bf16(f3.x); t1[5] = (short)f32_bf16(f3.y);
    t1[6] = (short)f32_bf16(f3.z); t1[7] = (short)f32_bf16(f3.w);
    *(bf16x8*)&Vb[r][s * 16] = t0;
    *(bf16x8*)&Vb[r][s * 16 + 8] = t1;
  }
  u16* kp = kpre + (size_t)h * 262144 + (size_t)t * 8192;
#pragma unroll
  for (int j = 0; j < 4; ++j) {
    int p = j * 256 + tid;
    int r = p >> 4;
    int g = (p & 15) ^ (r & 15);
    const float* srcp = k + ((size_t)(h * S_LEN + c0 + r)) * D_DIM + g * 8;
    float4 a = *(const float4*)srcp;
    float4 b = *(const float4*)(srcp + 4);
    bf16x8 o;
    o[0] = (short)f32_bf16(a.x); o[1] = (short)f32_bf16(a.y);
    o[2] = (short)f32_bf16(a.z); o[3] = (short)f32_bf16(a.w);
    o[4] = (short)f32_bf16(b.x); o[5] = (short)f32_bf16(b.y);
    o[6] = (short)f32_bf16(b.z); o[7] = (short)f32_bf16(b.w);
    *(bf16x8*)(kp + p * 8) = o;
  }
  __syncthreads();
  u16* vp = vpre + (size_t)h * 262144 + (size_t)t * 8192;
#pragma unroll
  for (int j = 0; j < 4; ++j) {
    int p = j * 256 + tid;
    int d = p >> 3;
    int cb = (p & 7) ^ (d & 7);
    bf16x8 g;
#pragma unroll
    for (int e = 0; e < 8; ++e) g[e] = (short)Vb[cb * 8 + e][d];
    *(bf16x8*)(vp + p * 8) = g;
  }
}

// ---------------- Stage 1a: est scores (f32 VALU — selection-stable; R7 verbatim) ----------------
__global__ __launch_bounds__(256) void est_kernel(const float* __restrict__ q,
                                                  const float* __restrict__ k,
                                                  float* __restrict__ scores) {
  int cc = blockIdx.x;
  int h = blockIdx.y;
  int tid = threadIdx.x;
  int ty = tid >> 4, tx = tid & 15;
  __shared__ float Qs[64][36];
  __shared__ float Ks[64][36];
  float acc[4][4];
#pragma unroll
  for (int i = 0; i < 4; ++i)
#pragma unroll
    for (int j = 0; j < 4; ++j) acc[i][j] = 0.f;
  const float* qbase = q + ((size_t)h * S_LEN + (S_LEN - LAST_Q)) * D_DIM;
  const float* kbase = k + ((size_t)h * S_LEN + cc * 64) * D_DIM;
  for (int dc = 0; dc < 4; ++dc) {
    __syncthreads();
    for (int i = tid; i < 512; i += 256) {
      int r = i >> 3, s = i & 7;
      float4 a = *(const float4*)(qbase + (size_t)r * D_DIM + dc * 32 + s * 4);
      *(float4*)&Qs[r][s * 4] = a;
      float4 b = *(const float4*)(kbase + (size_t)r * D_DIM + dc * 32 + s * 4);
      *(float4*)&Ks[r][s * 4] = b;
    }
    __syncthreads();
#pragma unroll
    for (int d4 = 0; d4 < 8; ++d4) {
      float4 qv[4], kv[4];
#pragma unroll
      for (int i = 0; i < 4; ++i) qv[i] = *(const float4*)&Qs[ty + 16 * i][d4 * 4];
#pragma unroll
      for (int j = 0; j < 4; ++j) kv[j] = *(const float4*)&Ks[tx + 16 * j][d4 * 4];
#pragma unroll
      for (int i = 0; i < 4; ++i)
#pragma unroll
        for (int j = 0; j < 4; ++j)
          acc[i][j] += qv[i].x * kv[j].x + qv[i].y * kv[j].y + qv[i].z * kv[j].z + qv[i].w * kv[j].w;
    }
  }
#pragma unroll
  for (int i = 0; i < 4; ++i) {
    int rl = ty + 16 * i;
    int rg = (S_LEN - LAST_Q) + rl;
#pragma unroll
    for (int j = 0; j < 4; ++j) {
      int cg = cc * 64 + tx + 16 * j;
      float vv = (cg <= rg) ? acc[i][j] * SCALE_F : -1e30f;
      scores[((size_t)h * LAST_Q + rl) * S_LEN + cg] = vv;
    }
  }
}

// ---------------- Stage 1b: softmax partials (grid 32 x 8, 8 rows each; R7 verbatim) ----------------
__global__ __launch_bounds__(256) void soft_partial_kernel(const float* __restrict__ scores,
                                                           float* __restrict__ part) {
  int h = blockIdx.x, rg = blockIdx.y;
  int tid = threadIdx.x;
  int wave = tid >> 6, lane = tid & 63;
  __shared__ float vs[2048];
  __shared__ float ss[2048];
  __shared__ float red[4];
  int i0 = tid * 8;
#pragma unroll
  for (int e = 0; e < 8; ++e) { vs[i0 + e] = 0.f; ss[i0 + e] = 0.f; }
  for (int rr = 0; rr < 8; ++rr) {
    int r = rg * 8 + rr;
    const float* sp = scores + ((size_t)h * LAST_Q + r) * S_LEN;
    float4 a = *(const float4*)(sp + i0);
    float4 b = *(const float4*)(sp + i0 + 4);
    float x[8] = {a.x, a.y, a.z, a.w, b.x, b.y, b.z, b.w};
    float wm = -1e30f;
#pragma unroll
    for (int e = 0; e < 8; ++e) wm = fmaxf(wm, x[e]);
#pragma unroll
    for (int mk = 1; mk < 64; mk <<= 1) wm = fmaxf(wm, __shfl_xor(wm, mk, 64));
    __syncthreads();
    if (lane == 0) red[wave] = wm;
    __syncthreads();
    float m = fmaxf(fmaxf(red[0], red[1]), fmaxf(red[2], red[3]));
    float psum = 0.f;
#pragma unroll
    for (int e = 0; e < 8; ++e) { x[e] = __expf(x[e] - m); psum += x[e]; }
#pragma unroll
    for (int mk = 1; mk < 64; mk <<= 1) psum += __shfl_xor(psum, mk, 64);
    __syncthreads();
    if (lane == 0) red[wave] = psum;
    __syncthreads();
    float inv = 1.f / (red[0] + red[1] + red[2] + red[3]);
    int rgl = (S_LEN - LAST_Q) + r;
#pragma unroll
    for (int e = 0; e < 8; ++e) {
      float p = x[e] * inv;
      int i = i0 + e;
      vs[i] += p;
      int d = rgl - i;
      if (d >= 0) ss[d] += p;
    }
  }
  __syncthreads();
  float* pb = part + ((size_t)(h * 8 + rg)) * 4096;
#pragma unroll
  for (int e = 0; e < 8; ++e) { pb[i0 + e] = vs[i0 + e]; pb[2048 + i0 + e] = ss[i0 + e]; }
}

// ---------------- Stage 1c: fused reduce + top-k -> bitmasks (R7 verbatim) ----------------
__global__ __launch_bounds__(256) void topk_kernel(const float* __restrict__ part,
                                                   u64* __restrict__ vbits,
                                                   u64* __restrict__ sbits) {
  int h = blockIdx.x;
  int which = blockIdx.y;
  u64* dst = which ? (sbits + h * 32) : (vbits + h * 32);
  u32 K = which ? 512u : 256u;
  int ninf = which ? 64 : 4;
  int tid = threadIdx.x;
  int lane = tid & 63, wid = tid >> 6;
  __shared__ u32 keys[2048];
  __shared__ u32 hist[256];
  __shared__ u32 wpart[4];
  __shared__ u32 sh_pref, sh_kth;
  __shared__ u64 mbw[32];
  int i0 = tid * 8;
  float accv[8] = {0.f, 0.f, 0.f, 0.f, 0.f, 0.f, 0.f, 0.f};
  for (int rg = 0; rg < 8; ++rg) {
    const float* pp = part + ((size_t)(h * 8 + rg)) * 4096 + which * 2048 + i0;
    float4 a = *(const float4*)pp;
    float4 b = *(const float4*)(pp + 4);
    accv[0] += a.x; accv[1] += a.y; accv[2] += a.z; accv[3] += a.w;
    accv[4] += b.x; accv[5] += b.y; accv[6] += b.z; accv[7] += b.w;
  }
#pragma unroll
  for (int e = 0; e < 8; ++e) {
    int i = i0 + e;
    keys[i] = (i < ninf) ? 0x7F800000u : __float_as_uint(accv[e]);
  }
  __syncthreads();
  u32 prefix = 0;
  u32 kth = K;
  for (int shift = 24; shift >= 0; shift -= 8) {
    hist[tid] = 0;
    __syncthreads();
#pragma unroll
    for (int e = 0; e < 8; ++e) {
      u32 kk = keys[i0 + e];
      if (shift == 24 || (kk >> (shift + 8)) == (prefix >> (shift + 8)))
        atomicAdd(&hist[(kk >> shift) & 255], 1u);
    }
    __syncthreads();
    u32 v = hist[tid];
    u32 x = v;
#pragma unroll
    for (int off = 1; off < 64; off <<= 1) {
      u32 o = __shfl_up(x, off, 64);
      if (lane >= off) x += o;
    }
    if (lane == 63) wpart[wid] = x;
    __syncthreads();
    u32 base = 0;
    for (int w2 = 0; w2 < wid; ++w2) base += wpart[w2];
    u32 T = wpart[0] + wpart[1] + wpart[2] + wpart[3];
    u32 Pincl = x + base;
    u32 Sb = T - Pincl + v;
    u32 Sn = T - Pincl;
    if (Sb >= kth && Sn < kth) {
      sh_pref = prefix | ((u32)tid << shift);
      sh_kth = kth - Sn;
    }
    __syncthreads();
    prefix = sh_pref;
    kth = sh_kth;
    __syncthreads();
  }
  u32 t = prefix;
  u32 cnt = 0;
#pragma unroll
  for (int e = 0; e < 8; ++e) cnt += (keys[i0 + e] == t) ? 1u : 0u;
  u32 x = cnt;
#pragma unroll
  for (int off = 1; off < 64; off <<= 1) {
    u32 o = __shfl_up(x, off, 64);
    if (lane >= off) x += o;
  }
  if (lane == 63) wpart[wid] = x;
  __syncthreads();
  u32 base = 0;
  for (int w2 = 0; w2 < wid; ++w2) base += wpart[w2];
  u32 exc = x + base - cnt;
  unsigned char myb = 0;
  u32 seen = 0;
#pragma unroll
  for (int e = 0; e < 8; ++e) {
    u32 kk = keys[i0 + e];
    bool in = (kk > t) || (kk == t && (exc + seen) < kth);
    if (kk == t) ++seen;
    myb |= (in ? 1u : 0u) << e;
  }
  ((unsigned char*)mbw)[tid] = myb;
  __syncthreads();
  if (tid < 32) dst[tid] = mbw[tid];
}

// ---------------- Stage 2: swapped-QK flash attention, DOUBLE-BUFFERED, 1 barrier/tile ----------------
// grid 1024 x 256 (4 waves). R7 head-grouped balanced map. Per tile: issue DMA(t+1) into
// the other LDS buffer, compute full tile from current buffer (~650cy covers L2 latency),
// then single vmcnt(0)+s_barrier. 64KB LDS -> 2 blocks/CU; barrier count 3->1 per tile.
template <bool PRE>
__global__ __launch_bounds__(256, 2) void attn_kernel(const float* __restrict__ q,
                                                      const float* __restrict__ kk,
                                                      const float* __restrict__ vv,
                                                      const u16* __restrict__ kpre,
                                                      const u16* __restrict__ vpre,
                                                      const u64* __restrict__ vbits,
                                                      const u64* __restrict__ sbits,
                                                      float* __restrict__ out) {
  int bid = blockIdx.x;
  int u = bid & 255, s = bid >> 8;
  int h = u & 31;
  int v_ = u >> 5;  // 0..7
  int qt;
  switch (s) {
    case 0: qt = v_; break;          // 0..7
    case 1: qt = 31 - v_; break;     // 24..31
    case 2: qt = v_ + 16; break;     // 16..23
    default: qt = 15 - v_; break;    // 8..15
  }
  int tid = threadIdx.x;
  int wave = tid >> 6, lane = tid & 63;
  int grp = lane >> 4, ln = lane & 15;

  __shared__ u16 Ks[2][8192];
  __shared__ u16 Vt[2][8192];
  __shared__ u64 smp[34];

  if (tid < 34) smp[tid] = (tid == 0 || tid == 33) ? 0ull : sbits[h * 32 + tid - 1];

  int q0w = qt * 64 + wave * 16;
  bf16x8 qf[4];
  const float* qrow = q + ((size_t)h * S_LEN + q0w + ln) * D_DIM;
#pragma unroll
  for (int ks = 0; ks < 4; ++ks) {
    const float* p = qrow + ks * 32 + grp * 8;
    float4 a = *(const float4*)p;
    float4 b = *(const float4*)(p + 4);
    bf16x8 f;
    f[0] = (short)f32_bf16(a.x * QSCALE); f[1] = (short)f32_bf16(a.y * QSCALE);
    f[2] = (short)f32_bf16(a.z * QSCALE); f[3] = (short)f32_bf16(a.w * QSCALE);
    f[4] = (short)f32_bf16(b.x * QSCALE); f[5] = (short)f32_bf16(b.y * QSCALE);
    f[6] = (short)f32_bf16(b.z * QSCALE); f[7] = (short)f32_bf16(b.w * QSCALE);
    qf[ks] = f;
  }
  f32x4 of[8];
#pragma unroll
  for (int i = 0; i < 8; ++i) of[i] = (f32x4){0.f, 0.f, 0.f, 0.f};
  float mr = -1e30f;
  float ls = 0.f;

  const int kb0 = (ln << 7) + (((0 + grp) ^ ln) << 3);
  const int kb1 = (ln << 7) + (((4 + grp) ^ ln) << 3);
  const int kb2 = (ln << 7) + (((8 + grp) ^ ln) << 3);
  const int kb3 = (ln << 7) + (((12 + grp) ^ ln) << 3);
  const int vb0 = (ln << 6) + (((0 + grp) ^ (ln & 7)) << 3);
  const int vb1 = (ln << 6) + (((4 + grp) ^ (ln & 7)) << 3);

  const u16* kp = kpre + (size_t)h * 262144;
  const u16* vp = vpre + (size_t)h * 262144;
  const float* kfb = kk + (size_t)h * S_LEN * D_DIM;
  const float* vfb = vv + (size_t)h * S_LEN * D_DIM;
  const u64* vwp = vbits + h * 32;
  int nt = qt + 1;
  int sb_lane = (lane & 48) + ((lane & 48) >> 2);

  auto dma_tile = [&](int t, int b) {
    const u16* ksrc = kp + (size_t)t * 8192;
    const u16* vsrc = vp + (size_t)t * 8192;
#pragma unroll
    for (int i = 0; i < 4; ++i) {
      int chunk = wave * 4 + i;
      __builtin_amdgcn_global_load_lds(
          (const __attribute__((address_space(1))) u32*)(const void*)(ksrc + (size_t)(chunk * 64 + lane) * 8),
          (__attribute__((address_space(3))) u32*)(void*)(&Ks[b][chunk * 512]), 16, 0, 0);
      __builtin_amdgcn_global_load_lds(
          (const __attribute__((address_space(1))) u32*)(const void*)(vsrc + (size_t)(chunk * 64 + lane) * 8),
          (__attribute__((address_space(3))) u32*)(void*)(&Vt[b][chunk * 512]), 16, 0, 0);
    }
  };

  if constexpr (PRE) {
    dma_tile(0, 0);
    asm volatile("s_waitcnt vmcnt(0)" ::: "memory");
  }
  __syncthreads();  // tile 0 + smp visible

  for (int t = 0; t < nt; ++t) {
    int cur = t & 1;
    if constexpr (PRE) {
      if (t + 1 < nt) dma_tile(t + 1, cur ^ 1);  // flies under this tile's compute
    } else {
      int c0f = t * 64;
      for (int i = tid; i < 512; i += 256) {
        int r = i >> 3, s2 = i & 7;
        const float* srcp = kfb + (size_t)(c0f + r) * D_DIM + s2 * 16;
        float4 f0 = *(const float4*)(srcp);
        float4 f1 = *(const float4*)(srcp + 4);
        float4 f2 = *(const float4*)(srcp + 8);
        float4 f3 = *(const float4*)(srcp + 12);
        bf16x8 t0v, t1v;
        t0v[0] = (short)f32_bf16(f0.x); t0v[1] = (short)f32_bf16(f0.y);
        t0v[2] = (short)f32_bf16(f0.z); t0v[3] = (short)f32_bf16(f0.w);
        t0v[4] = (short)f32_bf16(f1.x); t0v[5] = (short)f32_bf16(f1.y);
        t0v[6] = (short)f32_bf16(f1.z); t0v[7] = (short)f32_bf16(f1.w);
        t1v[0] = (short)f32_bf16(f2.x); t1v[1] = (short)f32_bf16(f2.y);
        t1v[2] = (short)f32_bf16(f2.z); t1v[3] = (short)f32_bf16(f2.w);
        t1v[4] = (short)f32_bf16(f3.x); t1v[5] = (short)f32_bf16(f3.y);
        t1v[6] = (short)f32_bf16(f3.z); t1v[7] = (short)f32_bf16(f3.w);
        int cb0 = s2 * 2, cb1 = s2 * 2 + 1;
        *(bf16x8*)&Ks[0][r * 128 + ((cb0 ^ (r & 15)) << 3)] = t0v;
        *(bf16x8*)&Ks[0][r * 128 + ((cb1 ^ (r & 15)) << 3)] = t1v;
      }
      for (int i = tid; i < 512; i += 256) {
        int r = i >> 3, s2 = i & 7;
        const float* srcp = vfb + (size_t)(c0f + r) * D_DIM + s2 * 16;
#pragma unroll
        for (int x = 0; x < 16; x += 4) {
          float4 f4 = *(const float4*)(srcp + x);
          int d0 = s2 * 16 + x;
          float vals[4] = {f4.x, f4.y, f4.z, f4.w};
#pragma unroll
          for (int y = 0; y < 4; ++y) {
            int d = d0 + y;
            Vt[0][d * 64 + (((r >> 3) ^ (d & 7)) << 3) + (r & 7)] = f32_bf16(vals[y]);
          }
        }
      }
      cur = 0;
      __syncthreads();
    }

    const u16* Kc = Ks[cur];
    const u16* Vc = Vt[cur];
    int c0 = t * 64;

    // ---- swapped QK^T ----
    f32x4 sfr[4];
#pragma unroll
    for (int nb = 0; nb < 4; ++nb) {
      f32x4 acc = (f32x4){0.f, 0.f, 0.f, 0.f};
      acc = __builtin_amdgcn_mfma_f32_16x16x32_bf16(*(const bf16x8*)&Kc[kb0 + nb * 2048], qf[0], acc, 0, 0, 0);
      acc = __builtin_amdgcn_mfma_f32_16x16x32_bf16(*(const bf16x8*)&Kc[kb1 + nb * 2048], qf[1], acc, 0, 0, 0);
      acc = __builtin_amdgcn_mfma_f32_16x16x32_bf16(*(const bf16x8*)&Kc[kb2 + nb * 2048], qf[2], acc, 0, 0, 0);
      acc = __builtin_amdgcn_mfma_f32_16x16x32_bf16(*(const bf16x8*)&Kc[kb3 + nb * 2048], qf[3], acc, 0, 0, 0);
      sfr[nb] = acc;
    }

    // ---- row max ----
    float tm = sfr[0][0];
#pragma unroll
    for (int nb = 0; nb < 4; ++nb)
#pragma unroll
      for (int jj = 0; jj < 4; ++jj) tm = fmaxf(tm, sfr[nb][jj]);
    tm = fmaxf(tm, __shfl_xor(tm, 16, 64));
    tm = fmaxf(tm, __shfl_xor(tm, 32, 64));

    // ---- deferred rescale (T13) ----
    if (__any(tm - mr > RESCALE_THR)) {
      float mn = fmaxf(mr, tm);
      float ex = __builtin_amdgcn_exp2f(mr - mn);
      mr = mn;
      ls *= ex;
      float e0 = __shfl(ex, sb_lane, 64);
      float e1 = __shfl(ex, sb_lane + 1, 64);
      float e2 = __shfl(ex, sb_lane + 2, 64);
      float e3 = __shfl(ex, sb_lane + 3, 64);
#pragma unroll
      for (int db = 0; db < 8; ++db) {
        of[db][0] *= e0; of[db][1] *= e1; of[db][2] *= e2; of[db][3] *= e3;
      }
    }

    // ---- mask + p = exp2 + pack ----
    int Cb = (q0w + ln) - c0 - (grp << 2);
    float rs = 0.f;
    u32 pkw[8];
    if (c0 >= q0w - 48) {
#pragma unroll
      for (int nb = 0; nb < 4; ++nb) {
        float pv[4];
#pragma unroll
        for (int jj = 0; jj < 4; ++jj) {
          bool keep = (16 * nb + jj) <= Cb;
          float p = keep ? __builtin_amdgcn_exp2f(sfr[nb][jj] - mr) : 0.f;
          rs += p;
          pv[jj] = p;
        }
        pkw[nb * 2] = cvt_pk_bf16(pv[0], pv[1]);
        pkw[nb * 2 + 1] = cvt_pk_bf16(pv[2], pv[3]);
      }
    } else {
      int b0 = Cb - 63;
      int w0i = (b0 >> 6) + 1;
      int sh = b0 & 63;
      u64 lo = smp[w0i];
      u64 hi = smp[w0i + 1];
      u64 W = (sh == 0) ? lo : ((lo >> sh) | (hi << (64 - sh)));
      u64 vword = vwp[t];
#pragma unroll
      for (int nb = 0; nb < 4; ++nb) {
        u32 vn = (u32)(vword >> (16 * nb + 4 * grp)) & 0xFu;
        u32 sn = (u32)(W >> (60 - 16 * nb)) & 0xFu;
        float pv[4];
#pragma unroll
        for (int jj = 0; jj < 4; ++jj) {
          u32 keep = ((vn >> jj) | (sn >> (3 - jj))) & 1u;
          float p = keep ? __builtin_amdgcn_exp2f(sfr[nb][jj] - mr) : 0.f;
          rs += p;
          pv[jj] = p;
        }
        pkw[nb * 2] = cvt_pk_bf16(pv[0], pv[1]);
        pkw[nb * 2 + 1] = cvt_pk_bf16(pv[2], pv[3]);
      }
    }
    rs += __shfl_xor(rs, 16, 64);
    rs += __shfl_xor(rs, 32, 64);
    ls += rs;

    // ---- PV ----
#pragma unroll
    for (int ks2 = 0; ks2 < 2; ++ks2) {
      int sl0 = ln + ((lane & 16) << 1);
      int sl1 = sl0 + 16;
      u32 a0 = __shfl(pkw[ks2 * 4 + 0], sl0, 64);
      u32 a1 = __shfl(pkw[ks2 * 4 + 1], sl0, 64);
      u32 a2 = __shfl(pkw[ks2 * 4 + 0], sl1, 64);
      u32 a3 = __shfl(pkw[ks2 * 4 + 1], sl1, 64);
      u32 b0_ = __shfl(pkw[ks2 * 4 + 2], sl0, 64);
      u32 b1_ = __shfl(pkw[ks2 * 4 + 3], sl0, 64);
      u32 b2_ = __shfl(pkw[ks2 * 4 + 2], sl1, 64);
      u32 b3_ = __shfl(pkw[ks2 * 4 + 3], sl1, 64);
      bool hi2 = grp >= 2;
      union { u32 w[4]; bf16x8 v; } pu;
      pu.w[0] = hi2 ? b0_ : a0;
      pu.w[1] = hi2 ? b1_ : a1;
      pu.w[2] = hi2 ? b2_ : a2;
      pu.w[3] = hi2 ? b3_ : a3;
      int vb = ks2 ? vb1 : vb0;
#pragma unroll
      for (int db = 0; db < 8; ++db) {
        bf16x8 vf = *(const bf16x8*)&Vc[vb + db * 1024];
        of[db] = __builtin_amdgcn_mfma_f32_16x16x32_bf16(pu.v, vf, of[db], 0, 0, 0);
      }
    }

    // ---- single rendezvous: t+1 DMAs landed (per-wave vmcnt) + all reads of buf[cur] done ----
    if constexpr (PRE) {
      if (t + 1 < nt) {
        __builtin_amdgcn_sched_barrier(0);
        asm volatile("s_waitcnt vmcnt(0)" ::: "memory");
        __builtin_amdgcn_s_barrier();
      }
    } else {
      __syncthreads();
    }
  }

  // ---- epilogue ----
  float invl = 1.f / ls;
  float i0 = __shfl(invl, sb_lane, 64);
  float i1 = __shfl(invl, sb_lane + 1, 64);
  float i2 = __shfl(invl, sb_lane + 2, 64);
  float i3 = __shfl(invl, sb_lane + 3, 64);
  float* ob = out + ((size_t)h * S_LEN + q0w) * D_DIM;
#pragma unroll
  for (int db = 0; db < 8; ++db) {
    ob[(size_t)(grp * 4 + 0) * D_DIM + db * 16 + ln] = of[db][0] * i0;
    ob[(size_t)(grp * 4 + 1) * D_DIM + db * 16 + ln] = of[db][1] * i1;
    ob[(size_t)(grp * 4 + 2) * D_DIM + db * 16 + ln] = of[db][2] * i2;
    ob[(size_t)(grp * 4 + 3) * D_DIM + db * 16 + ln] = of[db][3] * i3;
  }
}

extern "C" void kernel_launch(void* const* d_in, const int* in_sizes, int n_in,
                              void* d_out, int out_size, void* d_ws, size_t ws_size,
                              hipStream_t stream) {
  const float* q = (const float*)d_in[0];
  const float* k = (const float*)d_in[1];
  const float* v = (const float*)d_in[2];
  float* out = (float*)d_out;
  float* scores = out;                 // dead before attn writes begin
  float* part = out + 4194304;         // dead after topk
  u64* vbits = (u64*)d_ws;
  u64* sbits = vbits + 1024;
  const size_t PRE_NEED = 16384 + 2ull * 16777216;
  bool pre = ws_size >= PRE_NEED;
  u16* kpre = (u16*)((char*)d_ws + 16384);
  u16* vpre = kpre + 8388608;

  if (pre) conv_kernel<<<1024, 256, 0, stream>>>(k, v, kpre, vpre);
  est_kernel<<<dim3(32, 32), 256, 0, stream>>>(q, k, scores);
  soft_partial_kernel<<<dim3(32, 8), 256, 0, stream>>>(scores, part);
  topk_kernel<<<dim3(32, 2), 256, 0, stream>>>(part, vbits, sbits);
  if (pre)
    attn_kernel<true><<<1024, 256, 0, stream>>>(q, k, v, kpre, vpre, vbits, sbits, out);
  else
    attn_kernel<false><<<1024, 256, 0, stream>>>(q, k, v, kpre, vpre, vbits, sbits, out);
}

// Round 15
// 141.809 us; speedup vs baseline: 1.3493x; 1.0641x over previous
//
#include <hip/hip_runtime.h>
#include <hip/hip_bf16.h>

#define S_LEN 2048
#define NH 32
#define D_DIM 128
#define LAST_Q 64
#define SCALE_F 0.08838834764831845f
#define QSCALE (0.08838834764831845f * 1.4426950408889634f)  // scale * log2(e)
#define RESCALE_THR 11.54f

#if defined(__has_builtin)
#if __has_builtin(__builtin_amdgcn_mfma_f32_16x16x16bf16_1k)
#define HAVE_MFMA16 1
#endif
#endif

typedef __attribute__((ext_vector_type(8))) short bf16x8;
typedef __attribute__((ext_vector_type(4))) short s16x4;
typedef __attribute__((ext_vector_type(4))) float f32x4;
typedef unsigned long long u64;
typedef unsigned int u32;
typedef unsigned short u16;

static __device__ __forceinline__ u16 f32_bf16(float f) {
  u32 u = __float_as_uint(f);
  u32 r = (u + 0x7FFFu + ((u >> 16) & 1u)) >> 16;
  return (u16)r;
}

static __device__ __forceinline__ u32 cvt_pk_bf16(float lo, float hi) {
  u32 r;
  asm("v_cvt_pk_bf16_f32 %0, %1, %2" : "=v"(r) : "v"(lo), "v"(hi));
  return r;
}

// ---------------- Stage 0: preconvert to PRE-SWIZZLED bf16 layouts (R7 verbatim) ----------------
__global__ __launch_bounds__(256) void conv_kernel(const float* __restrict__ k,
                                                   const float* __restrict__ v,
                                                   u16* __restrict__ kpre,
                                                   u16* __restrict__ vpre) {
  int bid = blockIdx.x;
  int t = bid & 31, h = bid >> 5;
  int tid = threadIdx.x;
  int c0 = t * 64;
  __shared__ u16 Vb[64][136];
  for (int i = tid; i < 512; i += 256) {
    int r = i >> 3, s = i & 7;
    const float* srcp = v + ((size_t)(h * S_LEN + c0 + r)) * D_DIM + s * 16;
    float4 f0 = *(const float4*)(srcp);
    float4 f1 = *(const float4*)(srcp + 4);
    float4 f2 = *(const float4*)(srcp + 8);
    float4 f3 = *(const float4*)(srcp + 12);
    bf16x8 t0, t1;
    t0[0] = (short)f32_bf16(f0.x); t0[1] = (short)f32_bf16(f0.y);
    t0[2] = (short)f32_bf16(f0.z); t0[3] = (short)f32_bf16(f0.w);
    t0[4] = (short)f32_bf16(f1.x); t0[5] = (short)f32_bf16(f1.y);
    t0[6] = (short)f32_bf16(f1.z); t0[7] = (short)f32_bf16(f1.w);
    t1[0] = (short)f32_bf16(f2.x); t1[1] = (short)f32_bf16(f2.y);
    t1[2] = (short)f32_bf16(f2.z); t1[3] = (short)f32_bf16(f2.w);
    t1[4] = (short)f32_bf16(f3.x); t1[5] = (short)f32_bf16(f3.y);
    t1[6] = (short)f32_bf16(f3.z); t1[7] = (short)f32_bf16(f3.w);
    *(bf16x8*)&Vb[r][s * 16] = t0;
    *(bf16x8*)&Vb[r][s * 16 + 8] = t1;
  }
  u16* kp = kpre + (size_t)h * 262144 + (size_t)t * 8192;
#pragma unroll
  for (int j = 0; j < 4; ++j) {
    int p = j * 256 + tid;
    int r = p >> 4;
    int g = (p & 15) ^ (r & 15);
    const float* srcp = k + ((size_t)(h * S_LEN + c0 + r)) * D_DIM + g * 8;
    float4 a = *(const float4*)srcp;
    float4 b = *(const float4*)(srcp + 4);
    bf16x8 o;
    o[0] = (short)f32_bf16(a.x); o[1] = (short)f32_bf16(a.y);
    o[2] = (short)f32_bf16(a.z); o[3] = (short)f32_bf16(a.w);
    o[4] = (short)f32_bf16(b.x); o[5] = (short)f32_bf16(b.y);
    o[6] = (short)f32_bf16(b.z); o[7] = (short)f32_bf16(b.w);
    *(bf16x8*)(kp + p * 8) = o;
  }
  __syncthreads();
  u16* vp = vpre + (size_t)h * 262144 + (size_t)t * 8192;
#pragma unroll
  for (int j = 0; j < 4; ++j) {
    int p = j * 256 + tid;
    int d = p >> 3;
    int cb = (p & 7) ^ (d & 7);
    bf16x8 g;
#pragma unroll
    for (int e = 0; e < 8; ++e) g[e] = (short)Vb[cb * 8 + e][d];
    *(bf16x8*)(vp + p * 8) = g;
  }
}

// ---------------- Stage 1a: est scores (f32 VALU — selection-stable; R7 verbatim) ----------------
__global__ __launch_bounds__(256) void est_kernel(const float* __restrict__ q,
                                                  const float* __restrict__ k,
                                                  float* __restrict__ scores) {
  int cc = blockIdx.x;
  int h = blockIdx.y;
  int tid = threadIdx.x;
  int ty = tid >> 4, tx = tid & 15;
  __shared__ float Qs[64][36];
  __shared__ float Ks[64][36];
  float acc[4][4];
#pragma unroll
  for (int i = 0; i < 4; ++i)
#pragma unroll
    for (int j = 0; j < 4; ++j) acc[i][j] = 0.f;
  const float* qbase = q + ((size_t)h * S_LEN + (S_LEN - LAST_Q)) * D_DIM;
  const float* kbase = k + ((size_t)h * S_LEN + cc * 64) * D_DIM;
  for (int dc = 0; dc < 4; ++dc) {
    __syncthreads();
    for (int i = tid; i < 512; i += 256) {
      int r = i >> 3, s = i & 7;
      float4 a = *(const float4*)(qbase + (size_t)r * D_DIM + dc * 32 + s * 4);
      *(float4*)&Qs[r][s * 4] = a;
      float4 b = *(const float4*)(kbase + (size_t)r * D_DIM + dc * 32 + s * 4);
      *(float4*)&Ks[r][s * 4] = b;
    }
    __syncthreads();
#pragma unroll
    for (int d4 = 0; d4 < 8; ++d4) {
      float4 qv[4], kv[4];
#pragma unroll
      for (int i = 0; i < 4; ++i) qv[i] = *(const float4*)&Qs[ty + 16 * i][d4 * 4];
#pragma unroll
      for (int j = 0; j < 4; ++j) kv[j] = *(const float4*)&Ks[tx + 16 * j][d4 * 4];
#pragma unroll
      for (int i = 0; i < 4; ++i)
#pragma unroll
        for (int j = 0; j < 4; ++j)
          acc[i][j] += qv[i].x * kv[j].x + qv[i].y * kv[j].y + qv[i].z * kv[j].z + qv[i].w * kv[j].w;
    }
  }
#pragma unroll
  for (int i = 0; i < 4; ++i) {
    int rl = ty + 16 * i;
    int rg = (S_LEN - LAST_Q) + rl;
#pragma unroll
    for (int j = 0; j < 4; ++j) {
      int cg = cc * 64 + tx + 16 * j;
      float vv = (cg <= rg) ? acc[i][j] * SCALE_F : -1e30f;
      scores[((size_t)h * LAST_Q + rl) * S_LEN + cg] = vv;
    }
  }
}

// ---------------- Stage 1b: softmax partials (grid 32 x 8, 8 rows each; R7 verbatim) ----------------
__global__ __launch_bounds__(256) void soft_partial_kernel(const float* __restrict__ scores,
                                                           float* __restrict__ part) {
  int h = blockIdx.x, rg = blockIdx.y;
  int tid = threadIdx.x;
  int wave = tid >> 6, lane = tid & 63;
  __shared__ float vs[2048];
  __shared__ float ss[2048];
  __shared__ float red[4];
  int i0 = tid * 8;
#pragma unroll
  for (int e = 0; e < 8; ++e) { vs[i0 + e] = 0.f; ss[i0 + e] = 0.f; }
  for (int rr = 0; rr < 8; ++rr) {
    int r = rg * 8 + rr;
    const float* sp = scores + ((size_t)h * LAST_Q + r) * S_LEN;
    float4 a = *(const float4*)(sp + i0);
    float4 b = *(const float4*)(sp + i0 + 4);
    float x[8] = {a.x, a.y, a.z, a.w, b.x, b.y, b.z, b.w};
    float wm = -1e30f;
#pragma unroll
    for (int e = 0; e < 8; ++e) wm = fmaxf(wm, x[e]);
#pragma unroll
    for (int mk = 1; mk < 64; mk <<= 1) wm = fmaxf(wm, __shfl_xor(wm, mk, 64));
    __syncthreads();
    if (lane == 0) red[wave] = wm;
    __syncthreads();
    float m = fmaxf(fmaxf(red[0], red[1]), fmaxf(red[2], red[3]));
    float psum = 0.f;
#pragma unroll
    for (int e = 0; e < 8; ++e) { x[e] = __expf(x[e] - m); psum += x[e]; }
#pragma unroll
    for (int mk = 1; mk < 64; mk <<= 1) psum += __shfl_xor(psum, mk, 64);
    __syncthreads();
    if (lane == 0) red[wave] = psum;
    __syncthreads();
    float inv = 1.f / (red[0] + red[1] + red[2] + red[3]);
    int rgl = (S_LEN - LAST_Q) + r;
#pragma unroll
    for (int e = 0; e < 8; ++e) {
      float p = x[e] * inv;
      int i = i0 + e;
      vs[i] += p;
      int d = rgl - i;
      if (d >= 0) ss[d] += p;
    }
  }
  __syncthreads();
  float* pb = part + ((size_t)(h * 8 + rg)) * 4096;
#pragma unroll
  for (int e = 0; e < 8; ++e) { pb[i0 + e] = vs[i0 + e]; pb[2048 + i0 + e] = ss[i0 + e]; }
}

// ---------------- Stage 1c: fused reduce + top-k -> bitmasks (R7 verbatim) ----------------
__global__ __launch_bounds__(256) void topk_kernel(const float* __restrict__ part,
                                                   u64* __restrict__ vbits,
                                                   u64* __restrict__ sbits) {
  int h = blockIdx.x;
  int which = blockIdx.y;
  u64* dst = which ? (sbits + h * 32) : (vbits + h * 32);
  u32 K = which ? 512u : 256u;
  int ninf = which ? 64 : 4;
  int tid = threadIdx.x;
  int lane = tid & 63, wid = tid >> 6;
  __shared__ u32 keys[2048];
  __shared__ u32 hist[256];
  __shared__ u32 wpart[4];
  __shared__ u32 sh_pref, sh_kth;
  __shared__ u64 mbw[32];
  int i0 = tid * 8;
  float accv[8] = {0.f, 0.f, 0.f, 0.f, 0.f, 0.f, 0.f, 0.f};
  for (int rg = 0; rg < 8; ++rg) {
    const float* pp = part + ((size_t)(h * 8 + rg)) * 4096 + which * 2048 + i0;
    float4 a = *(const float4*)pp;
    float4 b = *(const float4*)(pp + 4);
    accv[0] += a.x; accv[1] += a.y; accv[2] += a.z; accv[3] += a.w;
    accv[4] += b.x; accv[5] += b.y; accv[6] += b.z; accv[7] += b.w;
  }
#pragma unroll
  for (int e = 0; e < 8; ++e) {
    int i = i0 + e;
    keys[i] = (i < ninf) ? 0x7F800000u : __float_as_uint(accv[e]);
  }
  __syncthreads();
  u32 prefix = 0;
  u32 kth = K;
  for (int shift = 24; shift >= 0; shift -= 8) {
    hist[tid] = 0;
    __syncthreads();
#pragma unroll
    for (int e = 0; e < 8; ++e) {
      u32 kk = keys[i0 + e];
      if (shift == 24 || (kk >> (shift + 8)) == (prefix >> (shift + 8)))
        atomicAdd(&hist[(kk >> shift) & 255], 1u);
    }
    __syncthreads();
    u32 v = hist[tid];
    u32 x = v;
#pragma unroll
    for (int off = 1; off < 64; off <<= 1) {
      u32 o = __shfl_up(x, off, 64);
      if (lane >= off) x += o;
    }
    if (lane == 63) wpart[wid] = x;
    __syncthreads();
    u32 base = 0;
    for (int w2 = 0; w2 < wid; ++w2) base += wpart[w2];
    u32 T = wpart[0] + wpart[1] + wpart[2] + wpart[3];
    u32 Pincl = x + base;
    u32 Sb = T - Pincl + v;
    u32 Sn = T - Pincl;
    if (Sb >= kth && Sn < kth) {
      sh_pref = prefix | ((u32)tid << shift);
      sh_kth = kth - Sn;
    }
    __syncthreads();
    prefix = sh_pref;
    kth = sh_kth;
    __syncthreads();
  }
  u32 t = prefix;
  u32 cnt = 0;
#pragma unroll
  for (int e = 0; e < 8; ++e) cnt += (keys[i0 + e] == t) ? 1u : 0u;
  u32 x = cnt;
#pragma unroll
  for (int off = 1; off < 64; off <<= 1) {
    u32 o = __shfl_up(x, off, 64);
    if (lane >= off) x += o;
  }
  if (lane == 63) wpart[wid] = x;
  __syncthreads();
  u32 base = 0;
  for (int w2 = 0; w2 < wid; ++w2) base += wpart[w2];
  u32 exc = x + base - cnt;
  unsigned char myb = 0;
  u32 seen = 0;
#pragma unroll
  for (int e = 0; e < 8; ++e) {
    u32 kk = keys[i0 + e];
    bool in = (kk > t) || (kk == t && (exc + seen) < kth);
    if (kk == t) ++seen;
    myb |= (in ? 1u : 0u) << e;
  }
  ((unsigned char*)mbw)[tid] = myb;
  __syncthreads();
  if (tid < 32) dst[tid] = mbw[tid];
}

// ---------------- Stage 2: R7 attn + shuffle-free PV via 16x16x16 MFMA ----------------
// Swapped-QK P (q=ln, k=4grp+jj per nb) is EXACTLY the A-operand layout of
// v_mfma_f32_16x16x16_bf16 -> PV feeds from registers, zero ds_bpermute.
template <bool PRE>
__global__ __launch_bounds__(256, 4) void attn_kernel(const float* __restrict__ q,
                                                      const float* __restrict__ kk,
                                                      const float* __restrict__ vv,
                                                      const u16* __restrict__ kpre,
                                                      const u16* __restrict__ vpre,
                                                      const u64* __restrict__ vbits,
                                                      const u64* __restrict__ sbits,
                                                      float* __restrict__ out) {
  int bid = blockIdx.x;
  int u = bid & 255, s = bid >> 8;
  int h = u & 31;
  int v_ = u >> 5;  // 0..7
  int qt;
  switch (s) {
    case 0: qt = v_; break;          // 0..7
    case 1: qt = 31 - v_; break;     // 24..31
    case 2: qt = v_ + 16; break;     // 16..23
    default: qt = 15 - v_; break;    // 8..15
  }
  int tid = threadIdx.x;
  int wave = tid >> 6, lane = tid & 63;
  int grp = lane >> 4, ln = lane & 15;

  __shared__ u16 Ks[8192];
  __shared__ u16 Vt[8192];
  __shared__ u64 smp[34];

  if (tid < 34) smp[tid] = (tid == 0 || tid == 33) ? 0ull : sbits[h * 32 + tid - 1];

  int q0w = qt * 64 + wave * 16;
  bf16x8 qf[4];
  const float* qrow = q + ((size_t)h * S_LEN + q0w + ln) * D_DIM;
#pragma unroll
  for (int ks = 0; ks < 4; ++ks) {
    const float* p = qrow + ks * 32 + grp * 8;
    float4 a = *(const float4*)p;
    float4 b = *(const float4*)(p + 4);
    bf16x8 f;
    f[0] = (short)f32_bf16(a.x * QSCALE); f[1] = (short)f32_bf16(a.y * QSCALE);
    f[2] = (short)f32_bf16(a.z * QSCALE); f[3] = (short)f32_bf16(a.w * QSCALE);
    f[4] = (short)f32_bf16(b.x * QSCALE); f[5] = (short)f32_bf16(b.y * QSCALE);
    f[6] = (short)f32_bf16(b.z * QSCALE); f[7] = (short)f32_bf16(b.w * QSCALE);
    qf[ks] = f;
  }
  f32x4 of[8];
#pragma unroll
  for (int i = 0; i < 8; ++i) of[i] = (f32x4){0.f, 0.f, 0.f, 0.f};
  float mr = -1e30f;
  float ls = 0.f;

  const int kb0 = (ln << 7) + (((0 + grp) ^ ln) << 3);
  const int kb1 = (ln << 7) + (((4 + grp) ^ ln) << 3);
  const int kb2 = (ln << 7) + (((8 + grp) ^ ln) << 3);
  const int kb3 = (ln << 7) + (((12 + grp) ^ ln) << 3);
#if HAVE_MFMA16
  // b64 V fragment bases per nb: c = 16nb + 4grp + e (e<4), d = db*16 + ln
  int vbm[4];
#pragma unroll
  for (int nb = 0; nb < 4; ++nb)
    vbm[nb] = (ln << 6) + ((((2 * nb) + (grp >> 1)) ^ (ln & 7)) << 3) + ((grp & 1) << 2);
#else
  const int vb0 = (ln << 6) + (((0 + grp) ^ (ln & 7)) << 3);
  const int vb1 = (ln << 6) + (((4 + grp) ^ (ln & 7)) << 3);
#endif

  const u16* kp = kpre + (size_t)h * 262144;
  const u16* vp = vpre + (size_t)h * 262144;
  const float* kfb = kk + (size_t)h * S_LEN * D_DIM;
  const float* vfb = vv + (size_t)h * S_LEN * D_DIM;
  const u64* vwp = vbits + h * 32;
  int nt = qt + 1;
  int sb_lane = (lane & 48) + ((lane & 48) >> 2);

  auto dma_k = [&](int t) {
    const u16* ksrc = kp + (size_t)t * 8192;
#pragma unroll
    for (int i = 0; i < 4; ++i) {
      int chunk = wave * 4 + i;
      __builtin_amdgcn_global_load_lds(
          (const __attribute__((address_space(1))) u32*)(const void*)(ksrc + (size_t)(chunk * 64 + lane) * 8),
          (__attribute__((address_space(3))) u32*)(void*)(&Ks[chunk * 512]), 16, 0, 0);
    }
  };
  auto dma_v = [&](int t) {
    const u16* vsrc = vp + (size_t)t * 8192;
#pragma unroll
    for (int i = 0; i < 4; ++i) {
      int chunk = wave * 4 + i;
      __builtin_amdgcn_global_load_lds(
          (const __attribute__((address_space(1))) u32*)(const void*)(vsrc + (size_t)(chunk * 64 + lane) * 8),
          (__attribute__((address_space(3))) u32*)(void*)(&Vt[chunk * 512]), 16, 0, 0);
    }
  };

  if constexpr (PRE) { dma_k(0); dma_v(0); }
  __syncthreads();  // drains prologue DMA + smp writes

  for (int t = 0; t < nt; ++t) {
    int c0 = t * 64;
    if constexpr (!PRE) {
      for (int i = tid; i < 512; i += 256) {
        int r = i >> 3, s2 = i & 7;
        const float* srcp = kfb + (size_t)(c0 + r) * D_DIM + s2 * 16;
        float4 f0 = *(const float4*)(srcp);
        float4 f1 = *(const float4*)(srcp + 4);
        float4 f2 = *(const float4*)(srcp + 8);
        float4 f3 = *(const float4*)(srcp + 12);
        bf16x8 t0v, t1v;
        t0v[0] = (short)f32_bf16(f0.x); t0v[1] = (short)f32_bf16(f0.y);
        t0v[2] = (short)f32_bf16(f0.z); t0v[3] = (short)f32_bf16(f0.w);
        t0v[4] = (short)f32_bf16(f1.x); t0v[5] = (short)f32_bf16(f1.y);
        t0v[6] = (short)f32_bf16(f1.z); t0v[7] = (short)f32_bf16(f1.w);
        t1v[0] = (short)f32_bf16(f2.x); t1v[1] = (short)f32_bf16(f2.y);
        t1v[2] = (short)f32_bf16(f2.z); t1v[3] = (short)f32_bf16(f2.w);
        t1v[4] = (short)f32_bf16(f3.x); t1v[5] = (short)f32_bf16(f3.y);
        t1v[6] = (short)f32_bf16(f3.z); t1v[7] = (short)f32_bf16(f3.w);
        int cb0 = s2 * 2, cb1 = s2 * 2 + 1;
        *(bf16x8*)&Ks[r * 128 + ((cb0 ^ (r & 15)) << 3)] = t0v;
        *(bf16x8*)&Ks[r * 128 + ((cb1 ^ (r & 15)) << 3)] = t1v;
      }
      for (int i = tid; i < 512; i += 256) {
        int r = i >> 3, s2 = i & 7;
        const float* srcp = vfb + (size_t)(c0 + r) * D_DIM + s2 * 16;
#pragma unroll
        for (int x = 0; x < 16; x += 4) {
          float4 f4 = *(const float4*)(srcp + x);
          int d0 = s2 * 16 + x;
          float vals[4] = {f4.x, f4.y, f4.z, f4.w};
#pragma unroll
          for (int y = 0; y < 4; ++y) {
            int d = d0 + y;
            Vt[d * 64 + (((r >> 3) ^ (d & 7)) << 3) + (r & 7)] = f32_bf16(vals[y]);
          }
        }
      }
      __syncthreads();
    }

    // ---- swapped QK^T ----
    f32x4 sfr[4];
#pragma unroll
    for (int nb = 0; nb < 4; ++nb) {
      f32x4 acc = (f32x4){0.f, 0.f, 0.f, 0.f};
      acc = __builtin_amdgcn_mfma_f32_16x16x32_bf16(*(const bf16x8*)&Ks[kb0 + nb * 2048], qf[0], acc, 0, 0, 0);
      acc = __builtin_amdgcn_mfma_f32_16x16x32_bf16(*(const bf16x8*)&Ks[kb1 + nb * 2048], qf[1], acc, 0, 0, 0);
      acc = __builtin_amdgcn_mfma_f32_16x16x32_bf16(*(const bf16x8*)&Ks[kb2 + nb * 2048], qf[2], acc, 0, 0, 0);
      acc = __builtin_amdgcn_mfma_f32_16x16x32_bf16(*(const bf16x8*)&Ks[kb3 + nb * 2048], qf[3], acc, 0, 0, 0);
      sfr[nb] = acc;
    }

    // ---- row max ----
    float tm = sfr[0][0];
#pragma unroll
    for (int nb = 0; nb < 4; ++nb)
#pragma unroll
      for (int jj = 0; jj < 4; ++jj) tm = fmaxf(tm, sfr[nb][jj]);
    tm = fmaxf(tm, __shfl_xor(tm, 16, 64));
    tm = fmaxf(tm, __shfl_xor(tm, 32, 64));

    // ---- deferred rescale (T13) ----
    if (__any(tm - mr > RESCALE_THR)) {
      float mn = fmaxf(mr, tm);
      float ex = __builtin_amdgcn_exp2f(mr - mn);
      mr = mn;
      ls *= ex;
      float e0 = __shfl(ex, sb_lane, 64);
      float e1 = __shfl(ex, sb_lane + 1, 64);
      float e2 = __shfl(ex, sb_lane + 2, 64);
      float e3 = __shfl(ex, sb_lane + 3, 64);
#pragma unroll
      for (int db = 0; db < 8; ++db) {
        of[db][0] *= e0; of[db][1] *= e1; of[db][2] *= e2; of[db][3] *= e3;
      }
    }

    // ---- mask + p = exp2 + pack (pa[nb] = A-operand of 16x16x16 PV) ----
    int Cb = (q0w + ln) - c0 - (grp << 2);
    float rs = 0.f;
    u32 paw[8];
    if (c0 >= q0w - 48) {
#pragma unroll
      for (int nb = 0; nb < 4; ++nb) {
        float pv[4];
#pragma unroll
        for (int jj = 0; jj < 4; ++jj) {
          bool keep = (16 * nb + jj) <= Cb;
          float p = keep ? __builtin_amdgcn_exp2f(sfr[nb][jj] - mr) : 0.f;
          rs += p;
          pv[jj] = p;
        }
        paw[nb * 2] = cvt_pk_bf16(pv[0], pv[1]);
        paw[nb * 2 + 1] = cvt_pk_bf16(pv[2], pv[3]);
      }
    } else {
      int b0 = Cb - 63;
      int w0i = (b0 >> 6) + 1;
      int sh = b0 & 63;
      u64 lo = smp[w0i];
      u64 hi = smp[w0i + 1];
      u64 W = (sh == 0) ? lo : ((lo >> sh) | (hi << (64 - sh)));
      u64 vword = vwp[t];
#pragma unroll
      for (int nb = 0; nb < 4; ++nb) {
        u32 vn = (u32)(vword >> (16 * nb + 4 * grp)) & 0xFu;
        u32 sn = (u32)(W >> (60 - 16 * nb)) & 0xFu;
        float pv[4];
#pragma unroll
        for (int jj = 0; jj < 4; ++jj) {
          u32 keep = ((vn >> jj) | (sn >> (3 - jj))) & 1u;
          float p = keep ? __builtin_amdgcn_exp2f(sfr[nb][jj] - mr) : 0.f;
          rs += p;
          pv[jj] = p;
        }
        paw[nb * 2] = cvt_pk_bf16(pv[0], pv[1]);
        paw[nb * 2 + 1] = cvt_pk_bf16(pv[2], pv[3]);
      }
    }
    rs += __shfl_xor(rs, 16, 64);
    rs += __shfl_xor(rs, 32, 64);
    ls += rs;

    // ---- BAR_A: Ks reads done + V(t) visible; prefetch K(t+1) ----
    if constexpr (PRE) {
      __builtin_amdgcn_sched_barrier(0);
      asm volatile("s_waitcnt vmcnt(0)" ::: "memory");
      __builtin_amdgcn_s_barrier();
      if (t + 1 < nt) dma_k(t + 1);
    }

    // ---- PV ----
#if HAVE_MFMA16
#pragma unroll
    for (int nb = 0; nb < 4; ++nb) {
      union { u32 w[2]; s16x4 v; } pa;
      pa.w[0] = paw[nb * 2];
      pa.w[1] = paw[nb * 2 + 1];
      int vb = vbm[nb];
#pragma unroll
      for (int db = 0; db < 8; ++db) {
        s16x4 vf = *(const s16x4*)&Vt[vb + db * 1024];
        of[db] = __builtin_amdgcn_mfma_f32_16x16x16bf16_1k(pa.v, vf, of[db], 0, 0, 0);
      }
    }
#else
#pragma unroll
    for (int ks2 = 0; ks2 < 2; ++ks2) {
      int sl0 = ln + ((lane & 16) << 1);
      int sl1 = sl0 + 16;
      u32 a0 = __shfl(paw[ks2 * 4 + 0], sl0, 64);
      u32 a1 = __shfl(paw[ks2 * 4 + 1], sl0, 64);
      u32 a2 = __shfl(paw[ks2 * 4 + 0], sl1, 64);
      u32 a3 = __shfl(paw[ks2 * 4 + 1], sl1, 64);
      u32 b0_ = __shfl(paw[ks2 * 4 + 2], sl0, 64);
      u32 b1_ = __shfl(paw[ks2 * 4 + 3], sl0, 64);
      u32 b2_ = __shfl(paw[ks2 * 4 + 2], sl1, 64);
      u32 b3_ = __shfl(paw[ks2 * 4 + 3], sl1, 64);
      bool hi2 = grp >= 2;
      union { u32 w[4]; bf16x8 v; } pu;
      pu.w[0] = hi2 ? b0_ : a0;
      pu.w[1] = hi2 ? b1_ : a1;
      pu.w[2] = hi2 ? b2_ : a2;
      pu.w[3] = hi2 ? b3_ : a3;
      int vb = ks2 ? vb1 : vb0;
#pragma unroll
      for (int db = 0; db < 8; ++db) {
        bf16x8 vf = *(const bf16x8*)&Vt[vb + db * 1024];
        of[db] = __builtin_amdgcn_mfma_f32_16x16x32_bf16(pu.v, vf, of[db], 0, 0, 0);
      }
    }
#endif

    // ---- BAR_B: Vt reads done; prefetch V(t+1); wait K(t+1); BAR_C ----
    if constexpr (PRE) {
      __builtin_amdgcn_sched_barrier(0);
      __builtin_amdgcn_s_barrier();
      if (t + 1 < nt) {
        dma_v(t + 1);
        asm volatile("s_waitcnt vmcnt(4)" ::: "memory");
      }
      __builtin_amdgcn_s_barrier();
    } else {
      __syncthreads();
    }
  }

  // ---- epilogue ----
  float invl = 1.f / ls;
  float i0 = __shfl(invl, sb_lane, 64);
  float i1 = __shfl(invl, sb_lane + 1, 64);
  float i2 = __shfl(invl, sb_lane + 2, 64);
  float i3 = __shfl(invl, sb_lane + 3, 64);
  float* ob = out + ((size_t)h * S_LEN + q0w) * D_DIM;
#pragma unroll
  for (int db = 0; db < 8; ++db) {
    ob[(size_t)(grp * 4 + 0) * D_DIM + db * 16 + ln] = of[db][0] * i0;
    ob[(size_t)(grp * 4 + 1) * D_DIM + db * 16 + ln] = of[db][1] * i1;
    ob[(size_t)(grp * 4 + 2) * D_DIM + db * 16 + ln] = of[db][2] * i2;
    ob[(size_t)(grp * 4 + 3) * D_DIM + db * 16 + ln] = of[db][3] * i3;
  }
}

extern "C" void kernel_launch(void* const* d_in, const int* in_sizes, int n_in,
                              void* d_out, int out_size, void* d_ws, size_t ws_size,
                              hipStream_t stream) {
  const float* q = (const float*)d_in[0];
  const float* k = (const float*)d_in[1];
  const float* v = (const float*)d_in[2];
  float* out = (float*)d_out;
  float* scores = out;
  float* part = out + 4194304;
  u64* vbits = (u64*)d_ws;
  u64* sbits = vbits + 1024;
  const size_t PRE_NEED = 16384 + 2ull * 16777216;
  bool pre = ws_size >= PRE_NEED;
  u16* kpre = (u16*)((char*)d_ws + 16384);
  u16* vpre = kpre + 8388608;

  if (pre) conv_kernel<<<1024, 256, 0, stream>>>(k, v, kpre, vpre);
  est_kernel<<<dim3(32, 32), 256, 0, stream>>>(q, k, scores);
  soft_partial_kernel<<<dim3(32, 8), 256, 0, stream>>>(scores, part);
  topk_kernel<<<dim3(32, 2), 256, 0, stream>>>(part, vbits, sbits);
  if (pre)
    attn_kernel<true><<<1024, 256, 0, stream>>>(q, k, v, kpre, vpre, vbits, sbits, out);
  else
    attn_kernel<false><<<1024, 256, 0, stream>>>(q, k, v, kpre, vpre, vbits, sbits, out);
}